// Round 10
// baseline (245.658 us; speedup 1.0000x reference)
//
#include <hip/hip_runtime.h>
#include <stdint.h>

#define HH   512
#define WW   1024
#define BB   2
#define NCC  34
#define PADK 7
#define TOPK 200
#define NSEG (TOPK + 1)
#define WPAD (WW + 2 * PADK)   // 1038
#define NPIX (HH * WW)         // 524288
#define CAP  12288
#define KSTG 1024              // LDS staging capacity for topk keys
#define INTMAXC  0x7FFFFFFF
#define INTMINC  (-0x7FFFFFFF - 1)

// ============================================================================
// R10 = R9 kernels UNCHANGED, but the full pipeline is launched TWICE per call.
// The pipeline is idempotent (k_clear re-zeroes all accumulators; every other
// buffer is unconditionally overwritten), so output is identical and the bench
// delta vs R9 measures exactly one pipeline pass (kernels + gaps), immune to
// any fixed per-iteration harness overhead. Calibration round.
// ============================================================================

struct Prm {
  const float* seg; const float* cr;
  float* out_final; float* out_segmap; float* out_instc; float* out_prob; float* out_cntf;
  int32_t* labA; int32_t* labB; float* pinv; uint8_t* segc;
  int* ymin; int* ymax; int* xmin; int* xmax;
  uint4* zero4; int nzero4;
  uint32_t* cand_cnt; uint32_t* cand_val; uint32_t* cand_idx;
  uint32_t* cnt0; uint32_t* cnt2; long long* sxq; long long* syq;
  uint32_t* hist; long long* Ssel;
};

// ---------------- K0: clear votes + accumulators, init min/max ----------------
__global__ __launch_bounds__(256) void k_clear(Prm p) {
  int t = blockIdx.x * 256 + threadIdx.x;
  if (t < BB * NPIX / 4) reinterpret_cast<uint4*>(p.labA)[t] = make_uint4(0u, 0u, 0u, 0u);
  if (t < p.nzero4) p.zero4[t] = make_uint4(0u, 0u, 0u, 0u);
  if (t < BB * NSEG) {
    p.ymin[t] = INTMAXC; p.ymax[t] = INTMINC; p.xmin[t] = INTMAXC; p.xmax[t] = INTMINC;
  }
}

// ---------------- K1: per-pixel pass (4 px/thread, single-exp softmax) ----------------
__global__ __launch_bounds__(256) void k_pixel(Prm p) {
  int t = blockIdx.x * 256 + threadIdx.x;
  int b = t >> 17;                                 // NPIX/4 = 2^17
  int pp = (t & 131071) << 2;
  int h = pp >> 10, w = pp & 1023;
  size_t i = (size_t)b * NPIX + pp;
  const float* base = p.seg + (size_t)b * NCC * NPIX + pp;
  float4 m = *reinterpret_cast<const float4*>(base);
  float4 s = make_float4(__expf(m.x), __expf(m.y), __expf(m.z), __expf(m.w));
  int4 am = make_int4(0, 0, 0, 0);
  #pragma unroll
  for (int c = 1; c < NCC; ++c) {
    float4 x = *reinterpret_cast<const float4*>(base + (size_t)c * NPIX);
    s.x += __expf(x.x); if (x.x > m.x) { m.x = x.x; am.x = c; }
    s.y += __expf(x.y); if (x.y > m.y) { m.y = x.y; am.y = c; }
    s.z += __expf(x.z); if (x.z > m.z) { m.z = x.z; am.z = c; }
    s.w += __expf(x.w); if (x.w > m.w) { m.w = x.w; am.w = c; }
  }
  *reinterpret_cast<float4*>(p.out_segmap + i) =
      make_float4((float)am.x, (float)am.y, (float)am.z, (float)am.w);
  *reinterpret_cast<uchar4*>(p.segc + i) =
      make_uchar4((unsigned char)am.x, (unsigned char)am.y, (unsigned char)am.z, (unsigned char)am.w);
  *reinterpret_cast<float4*>(p.pinv + i) =
      make_float4(1.f / s.x, 1.f / s.y, 1.f / s.z, 1.f / s.w);

  const float* c0 = p.cr + (size_t)b * 2 * NPIX + pp;
  float4 r0 = *reinterpret_cast<const float4*>(c0);
  float4 r1 = *reinterpret_cast<const float4*>(c0 + NPIX);
  float crx[4] = {r0.x, r0.y, r0.z, r0.w};
  float cry[4] = {r1.x, r1.y, r1.z, r1.w};
  int amA[4] = {am.x, am.y, am.z, am.w};
  int tgt[4];
  #pragma unroll
  for (int q = 0; q < 4; ++q) {
    tgt[q] = -1;
    if (amA[q] >= 24) {                            // "things": class in (23.99,33]
      float ccx = (float)(w + q + 1) - crx[q];
      float ccy = (float)(h + 1) - cry[q];
      float rx = rintf(ccx), ry = rintf(ccy);      // jnp.round (half-to-even)
      if (rx >= 0.f && ry >= 0.f && rx < (float)WW && ry < (float)HH)
        tgt[q] = (int)ry * WW + (int)rx;
    }
  }
  int lane = threadIdx.x & 63;
  uint32_t* vb = (uint32_t*)p.labA + (size_t)b * NPIX;
  #pragma unroll
  for (int q = 0; q < 4; ++q) {                    // wave-aggregated vote atomics
    int tq = tgt[q];
    unsigned long long act = __ballot(tq >= 0);
    while (act) {
      int leader = __ffsll(act) - 1;
      int tl = __shfl(tq, leader);
      unsigned long long mt = __ballot(tq == tl);
      if (lane == leader) atomicAdd(&vb[tl], (uint32_t)__popcll(mt & act));
      act &= ~mt;
    }
  }
}

// ---------------- K2: 7x7 NMS (4 px/thread), collect candidates ----------------
__global__ __launch_bounds__(256) void k_nms(Prm p) {
  int t = blockIdx.x * 256 + threadIdx.x;
  int b = t >> 17;
  int pp = (t & 131071) << 2;
  int h = pp >> 10, w0 = pp & 1023;
  const uint32_t* vb = (const uint32_t*)p.labA + (size_t)b * NPIX;
  uint4 v4 = *reinterpret_cast<const uint4*>(vb + pp);
  uint32_t vv[4] = {v4.x, v4.y, v4.z, v4.w};
  #pragma unroll
  for (int q = 0; q < 4; ++q) {
    uint32_t v = vv[q];
    if (v <= 50u) continue;                        // nms > 50.0 <=> count >= 51
    int w = w0 + q;
    bool peak = true;
    for (int dy = -3; dy <= 3 && peak; ++dy) {
      int yy = h + dy; if (yy < 0 || yy >= HH) continue;
      for (int dx = -3; dx <= 3; ++dx) {
        int xx = w + dx; if (xx < 0 || xx >= WW) continue;
        if (vb[yy * WW + xx] > v) { peak = false; break; }   // strict >
      }
    }
    if (!peak) continue;
    uint32_t pos = atomicAdd(&p.cand_cnt[b], 1u);
    if (pos < CAP) {
      p.cand_val[b * CAP + pos] = v;
      p.cand_idx[b * CAP + pos] = (uint32_t)((h + PADK) * WPAD + (w + PADK));  // PADDED
    }
  }
}

// ---------------- per-block redundant top-200 (lax.top_k tie order) ----------------
__device__ __forceinline__ int block_topk(const Prm& p, int b,
    unsigned long long* keysS, float* osx, float* osy) {
  int n = (int)p.cand_cnt[b]; if (n > CAP) n = CAP;
  const uint32_t* cv = p.cand_val + b * CAP;
  const uint32_t* ci = p.cand_idx + b * CAP;
  bool stg = (n <= KSTG);
  if (stg)
    for (int j = threadIdx.x; j < n; j += 256)
      keysS[j] = ((unsigned long long)cv[j] << 20) | (unsigned long long)(0xFFFFFu - ci[j]);
  __syncthreads();
  for (int i = threadIdx.x; i < n; i += 256) {
    unsigned long long ki = ((unsigned long long)cv[i] << 20) | (unsigned long long)(0xFFFFFu - ci[i]);
    int r = 0;
    if (stg) { for (int j = 0; j < n; ++j) r += (keysS[j] > ki) ? 1 : 0; }
    else {
      for (int j = 0; j < n; ++j) {
        unsigned long long kj = ((unsigned long long)cv[j] << 20) | (unsigned long long)(0xFFFFFu - ci[j]);
        r += (kj > ki) ? 1 : 0;                    // value desc, index asc (keys unique)
      }
    }
    if (r < TOPK) {
      uint32_t idx = ci[i];
      osx[r] = (float)(idx % WPAD);
      osy[r] = (float)(idx / WPAD);
    }
  }
  __syncthreads();
  return (n < TOPK) ? n : TOPK;
}

// ballot-scan compaction of good slots into distinct arrays; returns count.
__device__ __forceinline__ int block_compact(int good, const float* osx, const float* osy,
    float* dxs, float* dys, int* wsumS) {
  int lane = threadIdx.x & 63, wv = threadIdx.x >> 6;
  unsigned long long mask = __ballot(good);
  if (lane == 0) wsumS[wv] = (int)__popcll(mask);
  __syncthreads();
  int off = 0;
  #pragma unroll
  for (int t = 0; t < 4; ++t) off += (t < wv) ? wsumS[t] : 0;
  int total = wsumS[0] + wsumS[1] + wsumS[2] + wsumS[3];
  if (good) {
    int pos = off + (int)__popcll(mask & ((1ull << lane) - 1ull));
    dxs[pos] = osx[threadIdx.x]; dys[pos] = osy[threadIdx.x];
  }
  __syncthreads();
  return total;
}

// ---------------- per-wave conservative center prune ----------------
__device__ __forceinline__ int prune_centers(int n, const float* __restrict__ sxs,
    const float* __restrict__ sys, float minx, float maxx, float miny, float maxy,
    short* __restrict__ clist, int lane) {
  #pragma unroll
  for (int o = 32; o; o >>= 1) {
    minx = fminf(minx, __shfl_xor(minx, o));
    maxx = fmaxf(maxx, __shfl_xor(maxx, o));
    miny = fminf(miny, __shfl_xor(miny, o));
    maxy = fmaxf(maxy, __shfl_xor(maxy, o));
  }
  float cx0 = 0.5f * (minx + maxx), rx = 0.5f * (maxx - minx) + 0.5f;
  float cy0 = 0.5f * (miny + maxy), ry = 0.5f * (maxy - miny) + 0.5f;
  float lo[4];
  float ub = 3.4e38f;
  #pragma unroll
  for (int c = 0; c < 4; ++c) {
    int k = c * 64 + lane;
    float l = 3.4e38f;
    if (k < n) {
      float dx = fabsf(sxs[k] - cx0), dy = fabsf(sys[k] - cy0);
      float hx = dx + rx, hy = dy + ry;
      ub = fminf(ub, hx * hx + hy * hy);
      float lx = fmaxf(dx - rx, 0.f), ly = fmaxf(dy - ry, 0.f);
      l = lx * lx + ly * ly;
    }
    lo[c] = l;
  }
  #pragma unroll
  for (int o = 32; o; o >>= 1) ub = fminf(ub, __shfl_xor(ub, o));
  ub += 1.0f;
  int m = 0;
  unsigned long long lmlt = (1ull << lane) - 1ull;
  #pragma unroll
  for (int c = 0; c < 4; ++c) {                    // chunk-major => ascending k
    int k = c * 64 + lane;
    bool keep = (k < n) && (lo[c] <= ub);
    unsigned long long msk = __ballot(keep);
    if (keep) clist[m + (int)__popcll(msk & lmlt)] = (short)k;
    m += (int)__popcll(msk);
  }
  return m;
}

// exact argmin over pruned list (ascending original k, strict <), no-FMA math
__device__ __forceinline__ void assign4_exact(int m, const short* __restrict__ clist,
    const float* __restrict__ sxs, const float* __restrict__ sys,
    const float* ccx, const float* ccy, const unsigned char* cls, int* l) {
  float bd[4] = {3.4e38f, 3.4e38f, 3.4e38f, 3.4e38f};
  int bk[4] = {0, 0, 0, 0};
  for (int j = 0; j < m; ++j) {
    int k = (int)clist[j];
    float cxk = sxs[k], cyk = sys[k];
    #pragma unroll
    for (int q = 0; q < 4; ++q) {
      float dx = ccx[q] - cxk, dy = ccy[q] - cyk;
      float d = __fadd_rn(__fmul_rn(dx, dx), __fmul_rn(dy, dy));
      if (d < bd[q]) { bd[q] = d; bk[q] = k; }
    }
  }
  #pragma unroll
  for (int q = 0; q < 4; ++q) l[q] = (cls[q] >= 24) ? bk[q] + 1 : 0;
}

// shared assign body
__device__ __forceinline__ void assign_body(const Prm& p, int b, int h, int n,
    const float* sxs, const float* sys, short* clist_wv,
    const uchar4 sc4, const float4 r0, const float4 r1, int* l) {
  int w = threadIdx.x * 4;
  float ccx[4], ccy[4];
  #pragma unroll
  for (int q = 0; q < 4; ++q) {
    ccx[q] = (float)(w + q + 1) - ((const float*)&r0)[q];
    ccy[q] = (float)(h + 1) - ((const float*)&r1)[q];
  }
  float mnx = fminf(fminf(ccx[0], ccx[1]), fminf(ccx[2], ccx[3]));
  float mxx = fmaxf(fmaxf(ccx[0], ccx[1]), fmaxf(ccx[2], ccx[3]));
  float mny = fminf(fminf(ccy[0], ccy[1]), fminf(ccy[2], ccy[3]));
  float mxy = fmaxf(fmaxf(ccy[0], ccy[1]), fmaxf(ccy[2], ccy[3]));
  int lane = threadIdx.x & 63;
  int m = prune_centers(n, sxs, sys, mnx, mxx, mny, mxy, clist_wv, lane);
  unsigned char cls[4] = {sc4.x, sc4.y, sc4.z, sc4.w};
  assign4_exact(m, clist_wv, sxs, sys, ccx, ccy, cls, l);
}

// ---------------- K3: [topk] + assign0 + count/bbox (one row per block) ----------------
__global__ __launch_bounds__(256) void k_assign0(Prm p) {
  int b = blockIdx.y, h = blockIdx.x;
  __shared__ float sxs[TOPK], sys[TOPK];
  __shared__ short clists[4][TOPK];
  __shared__ uint32_t sc[NSEG];
  __shared__ int sx0[NSEG], sx1[NSEG];
  __shared__ unsigned long long keysS[KSTG];
  for (int j = threadIdx.x; j < NSEG; j += 256) { sc[j] = 0; sx0[j] = INTMAXC; sx1[j] = INTMINC; }
  int n = block_topk(p, b, keysS, sxs, sys);       // full top-k list, label k+1
  int w = threadIdx.x * 4;
  size_t i = (size_t)b * NPIX + h * WW + w;
  const float* c0 = p.cr + (size_t)b * 2 * NPIX + h * WW + w;
  uchar4 sc4 = *reinterpret_cast<const uchar4*>(p.segc + i);
  float4 r0 = *reinterpret_cast<const float4*>(c0);
  float4 r1 = *reinterpret_cast<const float4*>(c0 + NPIX);
  int l[4];
  if (n == 0) { l[0] = l[1] = l[2] = l[3] = 0; }   // any_c false -> lab0 = 0
  else assign_body(p, b, h, n, sxs, sys, clists[threadIdx.x >> 6], sc4, r0, r1, l);
  *reinterpret_cast<int4*>(p.labA + i) = make_int4(l[0], l[1], l[2], l[3]);
  int cur = -1; uint32_t rc = 0; int rx0 = 0, rx1 = 0;
  #pragma unroll
  for (int q = 0; q < 4; ++q) {                    // run-merged LDS atomics (skip label 0)
    int lq = l[q], x = w + q;
    if (lq == cur) { rc++; rx1 = x; }
    else {
      if (cur > 0) { atomicAdd(&sc[cur], rc); atomicMin(&sx0[cur], rx0); atomicMax(&sx1[cur], rx1); }
      cur = lq; rc = 1; rx0 = rx1 = x;
    }
  }
  if (cur > 0) { atomicAdd(&sc[cur], rc); atomicMin(&sx0[cur], rx0); atomicMax(&sx1[cur], rx1); }
  __syncthreads();
  for (int j = threadIdx.x; j < NSEG; j += 256) {
    if (sc[j]) {
      atomicAdd(&p.cnt0[b * NSEG + j], sc[j]);
      atomicMin(&p.ymin[b * NSEG + j], h); atomicMax(&p.ymax[b * NSEG + j], h);
      atomicMin(&p.xmin[b * NSEG + j], sx0[j]); atomicMax(&p.xmax[b * NSEG + j], sx1[j]);
    }
  }
}

// ---------------- K4: [topk + build1] + assign1 + count/cr-sums ----------------
__global__ __launch_bounds__(256) void k_assign1(Prm p) {
  int b = blockIdx.y, h = blockIdx.x;
  __shared__ float osx[TOPK], osy[TOPK];           // original slot coords
  __shared__ float sxs[TOPK], sys[TOPK];           // compacted good list
  __shared__ short clists[4][TOPK];
  __shared__ uint32_t sc[NSEG];
  __shared__ unsigned long long ssx[NSEG], ssy[NSEG];
  __shared__ unsigned long long keysS[KSTG];
  __shared__ int wsumS[4];
  for (int j = threadIdx.x; j < NSEG; j += 256) { sc[j] = 0; ssx[j] = 0; ssy[j] = 0; }
  block_topk(p, b, keysS, osx, osy);
  int k = threadIdx.x;
  int good = 0;
  if (k < TOPK) {                                  // bbox-ratio pruning (exact ints)
    uint32_t c = p.cnt0[b * NSEG + k + 1];
    if (c > 0) {
      int j = b * NSEG + k + 1;
      float area = (float)((p.ymax[j] - p.ymin[j] + 1) * (p.xmax[j] - p.xmin[j] + 1));
      float ratio = (float)c / area;               // same IEEE div as reference
      good = (ratio > 0.3f) ? 1 : 0;
    }
  }
  int n = block_compact(good, osx, osy, sxs, sys, wsumS);
  int w = threadIdx.x * 4;
  size_t i = (size_t)b * NPIX + h * WW + w;
  const float* c0 = p.cr + (size_t)b * 2 * NPIX + h * WW + w;
  uchar4 sc4 = *reinterpret_cast<const uchar4*>(p.segc + i);
  float4 r0 = *reinterpret_cast<const float4*>(c0);
  float4 r1 = *reinterpret_cast<const float4*>(c0 + NPIX);
  int l[4];
  if (n == 0) { int4 f = *reinterpret_cast<const int4*>(p.labA + i); l[0]=f.x; l[1]=f.y; l[2]=f.z; l[3]=f.w; }
  else assign_body(p, b, h, n, sxs, sys, clists[threadIdx.x >> 6], sc4, r0, r1, l);
  *reinterpret_cast<int4*>(p.labB + i) = make_int4(l[0], l[1], l[2], l[3]);
  float crx[4] = {r0.x, r0.y, r0.z, r0.w};
  float cry[4] = {r1.x, r1.y, r1.z, r1.w};
  int cur = -1; uint32_t rc = 0; long long ax = 0, ay = 0;
  #pragma unroll
  for (int q = 0; q < 4; ++q) {
    int lq = l[q];
    long long qx = __double2ll_rn((double)crx[q] * 1048576.0);   // 2^20 fixed-point
    long long qy = __double2ll_rn((double)cry[q] * 1048576.0);
    if (lq == cur) { rc++; ax += qx; ay += qy; }
    else {
      if (cur > 0) { atomicAdd(&sc[cur], rc);
                     atomicAdd(&ssx[cur], (unsigned long long)ax);
                     atomicAdd(&ssy[cur], (unsigned long long)ay); }
      cur = lq; rc = 1; ax = qx; ay = qy;
    }
  }
  if (cur > 0) { atomicAdd(&sc[cur], rc);
                 atomicAdd(&ssx[cur], (unsigned long long)ax);
                 atomicAdd(&ssy[cur], (unsigned long long)ay); }
  __syncthreads();
  for (int j = threadIdx.x; j < NSEG; j += 256) {
    if (sc[j]) {
      atomicAdd(&p.cnt2[b * NSEG + j], sc[j]);
      atomicAdd((unsigned long long*)&p.sxq[b * NSEG + j], ssx[j]);
      atomicAdd((unsigned long long*)&p.syq[b * NSEG + j], ssy[j]);
    }
  }
}

// ---------------- K5: [topk + build2] + assign2 + final + histogram ----------------
__global__ __launch_bounds__(256) void k_assign2(Prm p) {
  int b = blockIdx.y, h = blockIdx.x;
  __shared__ float osx[TOPK], osy[TOPK];
  __shared__ float sxs[TOPK], sys[TOPK];
  __shared__ short clists[4][TOPK];
  __shared__ uint32_t sh[NSEG * NCC];
  __shared__ unsigned long long keysS[KSTG];
  __shared__ int wsumS[4];
  for (int j = threadIdx.x; j < NSEG * NCC; j += 256) sh[j] = 0;
  block_topk(p, b, keysS, osx, osy);
  int k = threadIdx.x;
  int good = 0;
  if (k < TOPK) {                                  // mean pruning (COMPACT-space stats)
    uint32_t c = p.cnt2[b * NSEG + k + 1];
    if (c > 0) {
      double inv = 1.0 / (double)c;
      double mx = ((double)p.sxq[b * NSEG + k + 1] * (1.0 / 1048576.0)) * inv;
      double my = ((double)p.syq[b * NSEG + k + 1] * (1.0 / 1048576.0)) * inv;
      good = (fabs(mx) < 10.0 && fabs(my) < 10.0) ? 1 : 0;
    }
  }
  int n = block_compact(good, osx, osy, sxs, sys, wsumS);  // ORIGINAL sorted coords
  int w = threadIdx.x * 4;
  size_t i = (size_t)b * NPIX + h * WW + w;
  const float* c0 = p.cr + (size_t)b * 2 * NPIX + h * WW + w;
  uchar4 sc4 = *reinterpret_cast<const uchar4*>(p.segc + i);
  float4 r0 = *reinterpret_cast<const float4*>(c0);
  float4 r1 = *reinterpret_cast<const float4*>(c0 + NPIX);
  int l[4];
  if (n == 0) { int4 f = *reinterpret_cast<const int4*>(p.labB + i); l[0]=f.x; l[1]=f.y; l[2]=f.z; l[3]=f.w; }
  else assign_body(p, b, h, n, sxs, sys, clists[threadIdx.x >> 6], sc4, r0, r1, l);
  *reinterpret_cast<int4*>(p.labA + i) = make_int4(l[0], l[1], l[2], l[3]);
  *reinterpret_cast<float4*>(p.out_final + i) =
      make_float4((float)l[0], (float)l[1], (float)l[2], (float)l[3]);
  unsigned char cls[4] = {sc4.x, sc4.y, sc4.z, sc4.w};
  int curk = -1; uint32_t rc = 0;
  #pragma unroll
  for (int q = 0; q < 4; ++q) {                    // run-merged hist atomics
    int key = l[q] * NCC + (int)cls[q];
    if (key == curk) { rc++; }
    else { if (curk >= 0) atomicAdd(&sh[curk], rc); curk = key; rc = 1; }
  }
  if (curk >= 0) atomicAdd(&sh[curk], rc);
  __syncthreads();
  for (int j = threadIdx.x; j < NSEG * NCC; j += 256)
    if (sh[j]) atomicAdd(&p.hist[(size_t)b * NSEG * NCC + j], sh[j]);
}

// ---------------- K6: [mode] + prob-sum per label ----------------
__global__ __launch_bounds__(256) void k_sg(Prm p) {
  int b = blockIdx.y;
  __shared__ unsigned long long ss[NSEG];
  __shared__ int icS[NSEG];
  for (int j = threadIdx.x; j < NSEG; j += 256) {
    const uint32_t* hr = p.hist + ((size_t)b * NSEG + j) * NCC;
    uint32_t bv = hr[0], ssum = hr[0]; int bc = 0;
    #pragma unroll
    for (int c = 1; c < NCC; ++c) {
      uint32_t v = hr[c]; ssum += v;
      if (v > bv) { bv = v; bc = c; }              // first-max tie-break
    }
    icS[j] = bc;
    ss[j] = 0;
    if (blockIdx.x == 0) {                         // single writer per batch
      p.out_instc[b * NSEG + j] = (float)bc;
      p.out_cntf[b * NSEG + j] = (float)ssum;
    }
  }
  __syncthreads();
  int pp = (blockIdx.x * 256 + threadIdx.x) * 4;
  size_t i = (size_t)b * NPIX + pp;
  int4 l4 = *reinterpret_cast<const int4*>(p.labA + i);
  float4 iv = *reinterpret_cast<const float4*>(p.pinv + i);
  const float* sb = p.seg + (size_t)b * NCC * NPIX + pp;
  int lA[4] = {l4.x, l4.y, l4.z, l4.w};
  float ivA[4] = {iv.x, iv.y, iv.z, iv.w};
  int cur = -1; long long acc = 0;                 // label 0 IS included here
  #pragma unroll
  for (int q = 0; q < 4; ++q) {
    int lq = lA[q];
    int c = icS[lq];
    float x = sb[(size_t)c * NPIX + q];
    float pr = __expf(x) * ivA[q];                 // == exp(x - m)/sum(exp(x - m))
    long long qv = __double2ll_rn((double)pr * 4294967296.0);   // 2^32 fixed-point
    if (lq == cur) acc += qv;
    else { if (cur >= 0) atomicAdd(&ss[cur], (unsigned long long)acc); cur = lq; acc = qv; }
  }
  if (cur >= 0) atomicAdd(&ss[cur], (unsigned long long)acc);
  __syncthreads();
  for (int j = threadIdx.x; j < NSEG; j += 256)
    if (ss[j]) atomicAdd((unsigned long long*)&p.Ssel[b * NSEG + j], ss[j]);
}

// ---------------- K7: seg_prob = Ssel / max(cntf,1) ----------------
__global__ void k_prob(Prm p) {
  int i = blockIdx.x * blockDim.x + threadIdx.x;
  if (i >= BB * NSEG) return;
  double s = (double)p.Ssel[i] * (1.0 / 4294967296.0);
  float c = p.out_cntf[i];
  p.out_prob[i] = (float)(s / (double)fmaxf(c, 1.0f));
}

extern "C" void kernel_launch(void* const* d_in, const int* in_sizes, int n_in,
                              void* d_out, int out_size, void* d_ws, size_t ws_size,
                              hipStream_t stream) {
  float* out = (float*)d_out;
  Prm p;
  p.seg = (const float*)d_in[0];
  p.cr  = (const float*)d_in[2];
  p.out_final  = out;
  p.out_segmap = out + (size_t)BB * NPIX;
  p.out_instc  = out + (size_t)2 * BB * NPIX;
  p.out_prob   = p.out_instc + BB * NSEG;
  p.out_cntf   = p.out_prob + BB * NSEG;

  char* ws = (char*)d_ws;
  size_t off = 0;
  auto take = [&](size_t n) { size_t o = off; off += (n + 255) & ~(size_t)255; return o; };

  p.labA = (int32_t*)(ws + take((size_t)BB * NPIX * 4));  // votes -> lab0 -> final
  p.labB = (int32_t*)(ws + take((size_t)BB * NPIX * 4));  // lab1
  p.pinv = (float*)(ws + take((size_t)BB * NPIX * 4));
  p.segc = (uint8_t*)(ws + take((size_t)BB * NPIX));
  p.ymin = (int*)(ws + take(BB * NSEG * 4));               // INTMAX/MIN init (outside zero span)
  p.ymax = (int*)(ws + take(BB * NSEG * 4));
  p.xmin = (int*)(ws + take(BB * NSEG * 4));
  p.xmax = (int*)(ws + take(BB * NSEG * 4));

  size_t zero_begin = off;
  p.cand_cnt = (uint32_t*)(ws + take(BB * 4));
  p.cand_val = (uint32_t*)(ws + take((size_t)BB * CAP * 4));
  p.cand_idx = (uint32_t*)(ws + take((size_t)BB * CAP * 4));
  p.cnt0 = (uint32_t*)(ws + take(BB * NSEG * 4));
  p.cnt2 = (uint32_t*)(ws + take(BB * NSEG * 4));
  p.sxq = (long long*)(ws + take(BB * NSEG * 8));
  p.syq = (long long*)(ws + take(BB * NSEG * 8));
  p.hist = (uint32_t*)(ws + take((size_t)BB * NSEG * NCC * 4));
  p.Ssel = (long long*)(ws + take(BB * NSEG * 8));
  size_t zero_end = off;

  if (ws_size < off) return;  // workspace too small -> fail visibly

  p.zero4 = (uint4*)(ws + zero_begin);
  p.nzero4 = (int)((zero_end - zero_begin) / 16);  // 256-aligned span

  dim3 rgrid(HH, BB);
  // CALIBRATION: run the full (idempotent) pipeline TWICE.
  // Delta vs R9's single-pass total == true cost of one pass (kernels + gaps).
  for (int pass = 0; pass < 2; ++pass) {
    k_clear<<<BB * NPIX / 4 / 256, 256, 0, stream>>>(p);
    k_pixel<<<BB * NPIX / 4 / 256, 256, 0, stream>>>(p);
    k_nms<<<BB * NPIX / 4 / 256, 256, 0, stream>>>(p);
    k_assign0<<<rgrid, 256, 0, stream>>>(p);                 // + topk prologue
    k_assign1<<<rgrid, 256, 0, stream>>>(p);                 // + topk/build1 prologue
    k_assign2<<<rgrid, 256, 0, stream>>>(p);                 // + topk/build2 prologue
    k_sg<<<dim3(NPIX / 1024, BB), 256, 0, stream>>>(p);      // + mode prologue
    k_prob<<<(BB * NSEG + 255) / 256, 256, 0, stream>>>(p);
  }
}

// Round 11
// 156.216 us; speedup vs baseline: 1.5725x; 1.5725x over previous
//
#include <hip/hip_runtime.h>
#include <stdint.h>

#define HH   512
#define WW   1024
#define BB   2
#define NCC  34
#define PADK 7
#define TOPK 200
#define NSEG (TOPK + 1)
#define WPAD (WW + 2 * PADK)   // 1038
#define NPIX (HH * WW)         // 524288
#define CAP  12288
#define KSTG 1024              // LDS staging capacity for topk keys
#define INTMAXC  0x7FFFFFFF
#define INTMINC  (-0x7FFFFFFF - 1)

// ============================================================================
// R11 = R9 kernels UNCHANGED; {k_clear, k_pixel} launched TWICE (idempotent:
// clear re-zeroes votes/accumulators, pixel recomputes identical outputs).
// Bisection: Delta vs R9 = clear + k_pixel + 2 gaps. Pure calibration of the
// per-pixel pass (incl. its vote atomics), which the fill-masked top-5 hides.
// ============================================================================

struct Prm {
  const float* seg; const float* cr;
  float* out_final; float* out_segmap; float* out_instc; float* out_prob; float* out_cntf;
  int32_t* labA; int32_t* labB; float* pinv; uint8_t* segc;
  int* ymin; int* ymax; int* xmin; int* xmax;
  uint4* zero4; int nzero4;
  uint32_t* cand_cnt; uint32_t* cand_val; uint32_t* cand_idx;
  uint32_t* cnt0; uint32_t* cnt2; long long* sxq; long long* syq;
  uint32_t* hist; long long* Ssel;
};

// ---------------- K0: clear votes + accumulators, init min/max ----------------
__global__ __launch_bounds__(256) void k_clear(Prm p) {
  int t = blockIdx.x * 256 + threadIdx.x;
  if (t < BB * NPIX / 4) reinterpret_cast<uint4*>(p.labA)[t] = make_uint4(0u, 0u, 0u, 0u);
  if (t < p.nzero4) p.zero4[t] = make_uint4(0u, 0u, 0u, 0u);
  if (t < BB * NSEG) {
    p.ymin[t] = INTMAXC; p.ymax[t] = INTMINC; p.xmin[t] = INTMAXC; p.xmax[t] = INTMINC;
  }
}

// ---------------- K1: per-pixel pass (4 px/thread, single-exp softmax) ----------------
__global__ __launch_bounds__(256) void k_pixel(Prm p) {
  int t = blockIdx.x * 256 + threadIdx.x;
  int b = t >> 17;                                 // NPIX/4 = 2^17
  int pp = (t & 131071) << 2;
  int h = pp >> 10, w = pp & 1023;
  size_t i = (size_t)b * NPIX + pp;
  const float* base = p.seg + (size_t)b * NCC * NPIX + pp;
  float4 m = *reinterpret_cast<const float4*>(base);
  float4 s = make_float4(__expf(m.x), __expf(m.y), __expf(m.z), __expf(m.w));
  int4 am = make_int4(0, 0, 0, 0);
  #pragma unroll
  for (int c = 1; c < NCC; ++c) {
    float4 x = *reinterpret_cast<const float4*>(base + (size_t)c * NPIX);
    s.x += __expf(x.x); if (x.x > m.x) { m.x = x.x; am.x = c; }
    s.y += __expf(x.y); if (x.y > m.y) { m.y = x.y; am.y = c; }
    s.z += __expf(x.z); if (x.z > m.z) { m.z = x.z; am.z = c; }
    s.w += __expf(x.w); if (x.w > m.w) { m.w = x.w; am.w = c; }
  }
  *reinterpret_cast<float4*>(p.out_segmap + i) =
      make_float4((float)am.x, (float)am.y, (float)am.z, (float)am.w);
  *reinterpret_cast<uchar4*>(p.segc + i) =
      make_uchar4((unsigned char)am.x, (unsigned char)am.y, (unsigned char)am.z, (unsigned char)am.w);
  *reinterpret_cast<float4*>(p.pinv + i) =
      make_float4(1.f / s.x, 1.f / s.y, 1.f / s.z, 1.f / s.w);

  const float* c0 = p.cr + (size_t)b * 2 * NPIX + pp;
  float4 r0 = *reinterpret_cast<const float4*>(c0);
  float4 r1 = *reinterpret_cast<const float4*>(c0 + NPIX);
  float crx[4] = {r0.x, r0.y, r0.z, r0.w};
  float cry[4] = {r1.x, r1.y, r1.z, r1.w};
  int amA[4] = {am.x, am.y, am.z, am.w};
  int tgt[4];
  #pragma unroll
  for (int q = 0; q < 4; ++q) {
    tgt[q] = -1;
    if (amA[q] >= 24) {                            // "things": class in (23.99,33]
      float ccx = (float)(w + q + 1) - crx[q];
      float ccy = (float)(h + 1) - cry[q];
      float rx = rintf(ccx), ry = rintf(ccy);      // jnp.round (half-to-even)
      if (rx >= 0.f && ry >= 0.f && rx < (float)WW && ry < (float)HH)
        tgt[q] = (int)ry * WW + (int)rx;
    }
  }
  int lane = threadIdx.x & 63;
  uint32_t* vb = (uint32_t*)p.labA + (size_t)b * NPIX;
  #pragma unroll
  for (int q = 0; q < 4; ++q) {                    // wave-aggregated vote atomics
    int tq = tgt[q];
    unsigned long long act = __ballot(tq >= 0);
    while (act) {
      int leader = __ffsll(act) - 1;
      int tl = __shfl(tq, leader);
      unsigned long long mt = __ballot(tq == tl);
      if (lane == leader) atomicAdd(&vb[tl], (uint32_t)__popcll(mt & act));
      act &= ~mt;
    }
  }
}

// ---------------- K2: 7x7 NMS (4 px/thread), collect candidates ----------------
__global__ __launch_bounds__(256) void k_nms(Prm p) {
  int t = blockIdx.x * 256 + threadIdx.x;
  int b = t >> 17;
  int pp = (t & 131071) << 2;
  int h = pp >> 10, w0 = pp & 1023;
  const uint32_t* vb = (const uint32_t*)p.labA + (size_t)b * NPIX;
  uint4 v4 = *reinterpret_cast<const uint4*>(vb + pp);
  uint32_t vv[4] = {v4.x, v4.y, v4.z, v4.w};
  #pragma unroll
  for (int q = 0; q < 4; ++q) {
    uint32_t v = vv[q];
    if (v <= 50u) continue;                        // nms > 50.0 <=> count >= 51
    int w = w0 + q;
    bool peak = true;
    for (int dy = -3; dy <= 3 && peak; ++dy) {
      int yy = h + dy; if (yy < 0 || yy >= HH) continue;
      for (int dx = -3; dx <= 3; ++dx) {
        int xx = w + dx; if (xx < 0 || xx >= WW) continue;
        if (vb[yy * WW + xx] > v) { peak = false; break; }   // strict >
      }
    }
    if (!peak) continue;
    uint32_t pos = atomicAdd(&p.cand_cnt[b], 1u);
    if (pos < CAP) {
      p.cand_val[b * CAP + pos] = v;
      p.cand_idx[b * CAP + pos] = (uint32_t)((h + PADK) * WPAD + (w + PADK));  // PADDED
    }
  }
}

// ---------------- per-block redundant top-200 (lax.top_k tie order) ----------------
__device__ __forceinline__ int block_topk(const Prm& p, int b,
    unsigned long long* keysS, float* osx, float* osy) {
  int n = (int)p.cand_cnt[b]; if (n > CAP) n = CAP;
  const uint32_t* cv = p.cand_val + b * CAP;
  const uint32_t* ci = p.cand_idx + b * CAP;
  bool stg = (n <= KSTG);
  if (stg)
    for (int j = threadIdx.x; j < n; j += 256)
      keysS[j] = ((unsigned long long)cv[j] << 20) | (unsigned long long)(0xFFFFFu - ci[j]);
  __syncthreads();
  for (int i = threadIdx.x; i < n; i += 256) {
    unsigned long long ki = ((unsigned long long)cv[i] << 20) | (unsigned long long)(0xFFFFFu - ci[i]);
    int r = 0;
    if (stg) { for (int j = 0; j < n; ++j) r += (keysS[j] > ki) ? 1 : 0; }
    else {
      for (int j = 0; j < n; ++j) {
        unsigned long long kj = ((unsigned long long)cv[j] << 20) | (unsigned long long)(0xFFFFFu - ci[j]);
        r += (kj > ki) ? 1 : 0;                    // value desc, index asc (keys unique)
      }
    }
    if (r < TOPK) {
      uint32_t idx = ci[i];
      osx[r] = (float)(idx % WPAD);
      osy[r] = (float)(idx / WPAD);
    }
  }
  __syncthreads();
  return (n < TOPK) ? n : TOPK;
}

// ballot-scan compaction of good slots into distinct arrays; returns count.
__device__ __forceinline__ int block_compact(int good, const float* osx, const float* osy,
    float* dxs, float* dys, int* wsumS) {
  int lane = threadIdx.x & 63, wv = threadIdx.x >> 6;
  unsigned long long mask = __ballot(good);
  if (lane == 0) wsumS[wv] = (int)__popcll(mask);
  __syncthreads();
  int off = 0;
  #pragma unroll
  for (int t = 0; t < 4; ++t) off += (t < wv) ? wsumS[t] : 0;
  int total = wsumS[0] + wsumS[1] + wsumS[2] + wsumS[3];
  if (good) {
    int pos = off + (int)__popcll(mask & ((1ull << lane) - 1ull));
    dxs[pos] = osx[threadIdx.x]; dys[pos] = osy[threadIdx.x];
  }
  __syncthreads();
  return total;
}

// ---------------- per-wave conservative center prune ----------------
__device__ __forceinline__ int prune_centers(int n, const float* __restrict__ sxs,
    const float* __restrict__ sys, float minx, float maxx, float miny, float maxy,
    short* __restrict__ clist, int lane) {
  #pragma unroll
  for (int o = 32; o; o >>= 1) {
    minx = fminf(minx, __shfl_xor(minx, o));
    maxx = fmaxf(maxx, __shfl_xor(maxx, o));
    miny = fminf(miny, __shfl_xor(miny, o));
    maxy = fmaxf(maxy, __shfl_xor(maxy, o));
  }
  float cx0 = 0.5f * (minx + maxx), rx = 0.5f * (maxx - minx) + 0.5f;
  float cy0 = 0.5f * (miny + maxy), ry = 0.5f * (maxy - miny) + 0.5f;
  float lo[4];
  float ub = 3.4e38f;
  #pragma unroll
  for (int c = 0; c < 4; ++c) {
    int k = c * 64 + lane;
    float l = 3.4e38f;
    if (k < n) {
      float dx = fabsf(sxs[k] - cx0), dy = fabsf(sys[k] - cy0);
      float hx = dx + rx, hy = dy + ry;
      ub = fminf(ub, hx * hx + hy * hy);
      float lx = fmaxf(dx - rx, 0.f), ly = fmaxf(dy - ry, 0.f);
      l = lx * lx + ly * ly;
    }
    lo[c] = l;
  }
  #pragma unroll
  for (int o = 32; o; o >>= 1) ub = fminf(ub, __shfl_xor(ub, o));
  ub += 1.0f;
  int m = 0;
  unsigned long long lmlt = (1ull << lane) - 1ull;
  #pragma unroll
  for (int c = 0; c < 4; ++c) {                    // chunk-major => ascending k
    int k = c * 64 + lane;
    bool keep = (k < n) && (lo[c] <= ub);
    unsigned long long msk = __ballot(keep);
    if (keep) clist[m + (int)__popcll(msk & lmlt)] = (short)k;
    m += (int)__popcll(msk);
  }
  return m;
}

// exact argmin over pruned list (ascending original k, strict <), no-FMA math
__device__ __forceinline__ void assign4_exact(int m, const short* __restrict__ clist,
    const float* __restrict__ sxs, const float* __restrict__ sys,
    const float* ccx, const float* ccy, const unsigned char* cls, int* l) {
  float bd[4] = {3.4e38f, 3.4e38f, 3.4e38f, 3.4e38f};
  int bk[4] = {0, 0, 0, 0};
  for (int j = 0; j < m; ++j) {
    int k = (int)clist[j];
    float cxk = sxs[k], cyk = sys[k];
    #pragma unroll
    for (int q = 0; q < 4; ++q) {
      float dx = ccx[q] - cxk, dy = ccy[q] - cyk;
      float d = __fadd_rn(__fmul_rn(dx, dx), __fmul_rn(dy, dy));
      if (d < bd[q]) { bd[q] = d; bk[q] = k; }
    }
  }
  #pragma unroll
  for (int q = 0; q < 4; ++q) l[q] = (cls[q] >= 24) ? bk[q] + 1 : 0;
}

// shared assign body
__device__ __forceinline__ void assign_body(const Prm& p, int b, int h, int n,
    const float* sxs, const float* sys, short* clist_wv,
    const uchar4 sc4, const float4 r0, const float4 r1, int* l) {
  int w = threadIdx.x * 4;
  float ccx[4], ccy[4];
  #pragma unroll
  for (int q = 0; q < 4; ++q) {
    ccx[q] = (float)(w + q + 1) - ((const float*)&r0)[q];
    ccy[q] = (float)(h + 1) - ((const float*)&r1)[q];
  }
  float mnx = fminf(fminf(ccx[0], ccx[1]), fminf(ccx[2], ccx[3]));
  float mxx = fmaxf(fmaxf(ccx[0], ccx[1]), fmaxf(ccx[2], ccx[3]));
  float mny = fminf(fminf(ccy[0], ccy[1]), fminf(ccy[2], ccy[3]));
  float mxy = fmaxf(fmaxf(ccy[0], ccy[1]), fmaxf(ccy[2], ccy[3]));
  int lane = threadIdx.x & 63;
  int m = prune_centers(n, sxs, sys, mnx, mxx, mny, mxy, clist_wv, lane);
  unsigned char cls[4] = {sc4.x, sc4.y, sc4.z, sc4.w};
  assign4_exact(m, clist_wv, sxs, sys, ccx, ccy, cls, l);
}

// ---------------- K3: [topk] + assign0 + count/bbox (one row per block) ----------------
__global__ __launch_bounds__(256) void k_assign0(Prm p) {
  int b = blockIdx.y, h = blockIdx.x;
  __shared__ float sxs[TOPK], sys[TOPK];
  __shared__ short clists[4][TOPK];
  __shared__ uint32_t sc[NSEG];
  __shared__ int sx0[NSEG], sx1[NSEG];
  __shared__ unsigned long long keysS[KSTG];
  for (int j = threadIdx.x; j < NSEG; j += 256) { sc[j] = 0; sx0[j] = INTMAXC; sx1[j] = INTMINC; }
  int n = block_topk(p, b, keysS, sxs, sys);       // full top-k list, label k+1
  int w = threadIdx.x * 4;
  size_t i = (size_t)b * NPIX + h * WW + w;
  const float* c0 = p.cr + (size_t)b * 2 * NPIX + h * WW + w;
  uchar4 sc4 = *reinterpret_cast<const uchar4*>(p.segc + i);
  float4 r0 = *reinterpret_cast<const float4*>(c0);
  float4 r1 = *reinterpret_cast<const float4*>(c0 + NPIX);
  int l[4];
  if (n == 0) { l[0] = l[1] = l[2] = l[3] = 0; }   // any_c false -> lab0 = 0
  else assign_body(p, b, h, n, sxs, sys, clists[threadIdx.x >> 6], sc4, r0, r1, l);
  *reinterpret_cast<int4*>(p.labA + i) = make_int4(l[0], l[1], l[2], l[3]);
  int cur = -1; uint32_t rc = 0; int rx0 = 0, rx1 = 0;
  #pragma unroll
  for (int q = 0; q < 4; ++q) {                    // run-merged LDS atomics (skip label 0)
    int lq = l[q], x = w + q;
    if (lq == cur) { rc++; rx1 = x; }
    else {
      if (cur > 0) { atomicAdd(&sc[cur], rc); atomicMin(&sx0[cur], rx0); atomicMax(&sx1[cur], rx1); }
      cur = lq; rc = 1; rx0 = rx1 = x;
    }
  }
  if (cur > 0) { atomicAdd(&sc[cur], rc); atomicMin(&sx0[cur], rx0); atomicMax(&sx1[cur], rx1); }
  __syncthreads();
  for (int j = threadIdx.x; j < NSEG; j += 256) {
    if (sc[j]) {
      atomicAdd(&p.cnt0[b * NSEG + j], sc[j]);
      atomicMin(&p.ymin[b * NSEG + j], h); atomicMax(&p.ymax[b * NSEG + j], h);
      atomicMin(&p.xmin[b * NSEG + j], sx0[j]); atomicMax(&p.xmax[b * NSEG + j], sx1[j]);
    }
  }
}

// ---------------- K4: [topk + build1] + assign1 + count/cr-sums ----------------
__global__ __launch_bounds__(256) void k_assign1(Prm p) {
  int b = blockIdx.y, h = blockIdx.x;
  __shared__ float osx[TOPK], osy[TOPK];           // original slot coords
  __shared__ float sxs[TOPK], sys[TOPK];           // compacted good list
  __shared__ short clists[4][TOPK];
  __shared__ uint32_t sc[NSEG];
  __shared__ unsigned long long ssx[NSEG], ssy[NSEG];
  __shared__ unsigned long long keysS[KSTG];
  __shared__ int wsumS[4];
  for (int j = threadIdx.x; j < NSEG; j += 256) { sc[j] = 0; ssx[j] = 0; ssy[j] = 0; }
  block_topk(p, b, keysS, osx, osy);
  int k = threadIdx.x;
  int good = 0;
  if (k < TOPK) {                                  // bbox-ratio pruning (exact ints)
    uint32_t c = p.cnt0[b * NSEG + k + 1];
    if (c > 0) {
      int j = b * NSEG + k + 1;
      float area = (float)((p.ymax[j] - p.ymin[j] + 1) * (p.xmax[j] - p.xmin[j] + 1));
      float ratio = (float)c / area;               // same IEEE div as reference
      good = (ratio > 0.3f) ? 1 : 0;
    }
  }
  int n = block_compact(good, osx, osy, sxs, sys, wsumS);
  int w = threadIdx.x * 4;
  size_t i = (size_t)b * NPIX + h * WW + w;
  const float* c0 = p.cr + (size_t)b * 2 * NPIX + h * WW + w;
  uchar4 sc4 = *reinterpret_cast<const uchar4*>(p.segc + i);
  float4 r0 = *reinterpret_cast<const float4*>(c0);
  float4 r1 = *reinterpret_cast<const float4*>(c0 + NPIX);
  int l[4];
  if (n == 0) { int4 f = *reinterpret_cast<const int4*>(p.labA + i); l[0]=f.x; l[1]=f.y; l[2]=f.z; l[3]=f.w; }
  else assign_body(p, b, h, n, sxs, sys, clists[threadIdx.x >> 6], sc4, r0, r1, l);
  *reinterpret_cast<int4*>(p.labB + i) = make_int4(l[0], l[1], l[2], l[3]);
  float crx[4] = {r0.x, r0.y, r0.z, r0.w};
  float cry[4] = {r1.x, r1.y, r1.z, r1.w};
  int cur = -1; uint32_t rc = 0; long long ax = 0, ay = 0;
  #pragma unroll
  for (int q = 0; q < 4; ++q) {
    int lq = l[q];
    long long qx = __double2ll_rn((double)crx[q] * 1048576.0);   // 2^20 fixed-point
    long long qy = __double2ll_rn((double)cry[q] * 1048576.0);
    if (lq == cur) { rc++; ax += qx; ay += qy; }
    else {
      if (cur > 0) { atomicAdd(&sc[cur], rc);
                     atomicAdd(&ssx[cur], (unsigned long long)ax);
                     atomicAdd(&ssy[cur], (unsigned long long)ay); }
      cur = lq; rc = 1; ax = qx; ay = qy;
    }
  }
  if (cur > 0) { atomicAdd(&sc[cur], rc);
                 atomicAdd(&ssx[cur], (unsigned long long)ax);
                 atomicAdd(&ssy[cur], (unsigned long long)ay); }
  __syncthreads();
  for (int j = threadIdx.x; j < NSEG; j += 256) {
    if (sc[j]) {
      atomicAdd(&p.cnt2[b * NSEG + j], sc[j]);
      atomicAdd((unsigned long long*)&p.sxq[b * NSEG + j], ssx[j]);
      atomicAdd((unsigned long long*)&p.syq[b * NSEG + j], ssy[j]);
    }
  }
}

// ---------------- K5: [topk + build2] + assign2 + final + histogram ----------------
__global__ __launch_bounds__(256) void k_assign2(Prm p) {
  int b = blockIdx.y, h = blockIdx.x;
  __shared__ float osx[TOPK], osy[TOPK];
  __shared__ float sxs[TOPK], sys[TOPK];
  __shared__ short clists[4][TOPK];
  __shared__ uint32_t sh[NSEG * NCC];
  __shared__ unsigned long long keysS[KSTG];
  __shared__ int wsumS[4];
  for (int j = threadIdx.x; j < NSEG * NCC; j += 256) sh[j] = 0;
  block_topk(p, b, keysS, osx, osy);
  int k = threadIdx.x;
  int good = 0;
  if (k < TOPK) {                                  // mean pruning (COMPACT-space stats)
    uint32_t c = p.cnt2[b * NSEG + k + 1];
    if (c > 0) {
      double inv = 1.0 / (double)c;
      double mx = ((double)p.sxq[b * NSEG + k + 1] * (1.0 / 1048576.0)) * inv;
      double my = ((double)p.syq[b * NSEG + k + 1] * (1.0 / 1048576.0)) * inv;
      good = (fabs(mx) < 10.0 && fabs(my) < 10.0) ? 1 : 0;
    }
  }
  int n = block_compact(good, osx, osy, sxs, sys, wsumS);  // ORIGINAL sorted coords
  int w = threadIdx.x * 4;
  size_t i = (size_t)b * NPIX + h * WW + w;
  const float* c0 = p.cr + (size_t)b * 2 * NPIX + h * WW + w;
  uchar4 sc4 = *reinterpret_cast<const uchar4*>(p.segc + i);
  float4 r0 = *reinterpret_cast<const float4*>(c0);
  float4 r1 = *reinterpret_cast<const float4*>(c0 + NPIX);
  int l[4];
  if (n == 0) { int4 f = *reinterpret_cast<const int4*>(p.labB + i); l[0]=f.x; l[1]=f.y; l[2]=f.z; l[3]=f.w; }
  else assign_body(p, b, h, n, sxs, sys, clists[threadIdx.x >> 6], sc4, r0, r1, l);
  *reinterpret_cast<int4*>(p.labA + i) = make_int4(l[0], l[1], l[2], l[3]);
  *reinterpret_cast<float4*>(p.out_final + i) =
      make_float4((float)l[0], (float)l[1], (float)l[2], (float)l[3]);
  unsigned char cls[4] = {sc4.x, sc4.y, sc4.z, sc4.w};
  int curk = -1; uint32_t rc = 0;
  #pragma unroll
  for (int q = 0; q < 4; ++q) {                    // run-merged hist atomics
    int key = l[q] * NCC + (int)cls[q];
    if (key == curk) { rc++; }
    else { if (curk >= 0) atomicAdd(&sh[curk], rc); curk = key; rc = 1; }
  }
  if (curk >= 0) atomicAdd(&sh[curk], rc);
  __syncthreads();
  for (int j = threadIdx.x; j < NSEG * NCC; j += 256)
    if (sh[j]) atomicAdd(&p.hist[(size_t)b * NSEG * NCC + j], sh[j]);
}

// ---------------- K6: [mode] + prob-sum per label ----------------
__global__ __launch_bounds__(256) void k_sg(Prm p) {
  int b = blockIdx.y;
  __shared__ unsigned long long ss[NSEG];
  __shared__ int icS[NSEG];
  for (int j = threadIdx.x; j < NSEG; j += 256) {
    const uint32_t* hr = p.hist + ((size_t)b * NSEG + j) * NCC;
    uint32_t bv = hr[0], ssum = hr[0]; int bc = 0;
    #pragma unroll
    for (int c = 1; c < NCC; ++c) {
      uint32_t v = hr[c]; ssum += v;
      if (v > bv) { bv = v; bc = c; }              // first-max tie-break
    }
    icS[j] = bc;
    ss[j] = 0;
    if (blockIdx.x == 0) {                         // single writer per batch
      p.out_instc[b * NSEG + j] = (float)bc;
      p.out_cntf[b * NSEG + j] = (float)ssum;
    }
  }
  __syncthreads();
  int pp = (blockIdx.x * 256 + threadIdx.x) * 4;
  size_t i = (size_t)b * NPIX + pp;
  int4 l4 = *reinterpret_cast<const int4*>(p.labA + i);
  float4 iv = *reinterpret_cast<const float4*>(p.pinv + i);
  const float* sb = p.seg + (size_t)b * NCC * NPIX + pp;
  int lA[4] = {l4.x, l4.y, l4.z, l4.w};
  float ivA[4] = {iv.x, iv.y, iv.z, iv.w};
  int cur = -1; long long acc = 0;                 // label 0 IS included here
  #pragma unroll
  for (int q = 0; q < 4; ++q) {
    int lq = lA[q];
    int c = icS[lq];
    float x = sb[(size_t)c * NPIX + q];
    float pr = __expf(x) * ivA[q];                 // == exp(x - m)/sum(exp(x - m))
    long long qv = __double2ll_rn((double)pr * 4294967296.0);   // 2^32 fixed-point
    if (lq == cur) acc += qv;
    else { if (cur >= 0) atomicAdd(&ss[cur], (unsigned long long)acc); cur = lq; acc = qv; }
  }
  if (cur >= 0) atomicAdd(&ss[cur], (unsigned long long)acc);
  __syncthreads();
  for (int j = threadIdx.x; j < NSEG; j += 256)
    if (ss[j]) atomicAdd((unsigned long long*)&p.Ssel[b * NSEG + j], ss[j]);
}

// ---------------- K7: seg_prob = Ssel / max(cntf,1) ----------------
__global__ void k_prob(Prm p) {
  int i = blockIdx.x * blockDim.x + threadIdx.x;
  if (i >= BB * NSEG) return;
  double s = (double)p.Ssel[i] * (1.0 / 4294967296.0);
  float c = p.out_cntf[i];
  p.out_prob[i] = (float)(s / (double)fmaxf(c, 1.0f));
}

extern "C" void kernel_launch(void* const* d_in, const int* in_sizes, int n_in,
                              void* d_out, int out_size, void* d_ws, size_t ws_size,
                              hipStream_t stream) {
  float* out = (float*)d_out;
  Prm p;
  p.seg = (const float*)d_in[0];
  p.cr  = (const float*)d_in[2];
  p.out_final  = out;
  p.out_segmap = out + (size_t)BB * NPIX;
  p.out_instc  = out + (size_t)2 * BB * NPIX;
  p.out_prob   = p.out_instc + BB * NSEG;
  p.out_cntf   = p.out_prob + BB * NSEG;

  char* ws = (char*)d_ws;
  size_t off = 0;
  auto take = [&](size_t n) { size_t o = off; off += (n + 255) & ~(size_t)255; return o; };

  p.labA = (int32_t*)(ws + take((size_t)BB * NPIX * 4));  // votes -> lab0 -> final
  p.labB = (int32_t*)(ws + take((size_t)BB * NPIX * 4));  // lab1
  p.pinv = (float*)(ws + take((size_t)BB * NPIX * 4));
  p.segc = (uint8_t*)(ws + take((size_t)BB * NPIX));
  p.ymin = (int*)(ws + take(BB * NSEG * 4));               // INTMAX/MIN init (outside zero span)
  p.ymax = (int*)(ws + take(BB * NSEG * 4));
  p.xmin = (int*)(ws + take(BB * NSEG * 4));
  p.xmax = (int*)(ws + take(BB * NSEG * 4));

  size_t zero_begin = off;
  p.cand_cnt = (uint32_t*)(ws + take(BB * 4));
  p.cand_val = (uint32_t*)(ws + take((size_t)BB * CAP * 4));
  p.cand_idx = (uint32_t*)(ws + take((size_t)BB * CAP * 4));
  p.cnt0 = (uint32_t*)(ws + take(BB * NSEG * 4));
  p.cnt2 = (uint32_t*)(ws + take(BB * NSEG * 4));
  p.sxq = (long long*)(ws + take(BB * NSEG * 8));
  p.syq = (long long*)(ws + take(BB * NSEG * 8));
  p.hist = (uint32_t*)(ws + take((size_t)BB * NSEG * NCC * 4));
  p.Ssel = (long long*)(ws + take(BB * NSEG * 8));
  size_t zero_end = off;

  if (ws_size < off) return;  // workspace too small -> fail visibly

  p.zero4 = (uint4*)(ws + zero_begin);
  p.nzero4 = (int)((zero_end - zero_begin) / 16);  // 256-aligned span

  dim3 rgrid(HH, BB);
  // BISECT: run {clear, pixel} twice (idempotent pair).
  // Delta vs R9 = clear + k_pixel + 2 gaps.
  k_clear<<<BB * NPIX / 4 / 256, 256, 0, stream>>>(p);
  k_pixel<<<BB * NPIX / 4 / 256, 256, 0, stream>>>(p);
  k_clear<<<BB * NPIX / 4 / 256, 256, 0, stream>>>(p);
  k_pixel<<<BB * NPIX / 4 / 256, 256, 0, stream>>>(p);
  k_nms<<<BB * NPIX / 4 / 256, 256, 0, stream>>>(p);
  k_assign0<<<rgrid, 256, 0, stream>>>(p);                 // + topk prologue
  k_assign1<<<rgrid, 256, 0, stream>>>(p);                 // + topk/build1 prologue
  k_assign2<<<rgrid, 256, 0, stream>>>(p);                 // + topk/build2 prologue
  k_sg<<<dim3(NPIX / 1024, BB), 256, 0, stream>>>(p);      // + mode prologue
  k_prob<<<(BB * NSEG + 255) / 256, 256, 0, stream>>>(p);
}

// Round 12
// 144.611 us; speedup vs baseline: 1.6987x; 1.0803x over previous
//
#include <hip/hip_runtime.h>
#include <stdint.h>

#define HH   512
#define WW   1024
#define BB   2
#define NCC  34
#define PADK 7
#define TOPK 200
#define NSEG (TOPK + 1)
#define WPAD (WW + 2 * PADK)   // 1038
#define NPIX (HH * WW)         // 524288
#define CAP  12288
#define KSTG 1024              // LDS staging capacity for topk keys
#define INTMAXC  0x7FFFFFFF
#define INTMINC  (-0x7FFFFFFF - 1)

// ============================================================================
// R12 = R9 kernels UNCHANGED; k_assign1 launched TWICE. Second run rewrites
// identical labB and exactly doubles cnt2/sxq/syq, which is invariant for the
// downstream test (c>0 and (2sx)*(1/(2c)) == sx*(1/c) exactly in IEEE double).
// Bisection: Delta vs R9 = one assign pass + 1 gap.
// ============================================================================

struct Prm {
  const float* seg; const float* cr;
  float* out_final; float* out_segmap; float* out_instc; float* out_prob; float* out_cntf;
  int32_t* labA; int32_t* labB; float* pinv; uint8_t* segc;
  int* ymin; int* ymax; int* xmin; int* xmax;
  uint4* zero4; int nzero4;
  uint32_t* cand_cnt; uint32_t* cand_val; uint32_t* cand_idx;
  uint32_t* cnt0; uint32_t* cnt2; long long* sxq; long long* syq;
  uint32_t* hist; long long* Ssel;
};

// ---------------- K0: clear votes + accumulators, init min/max ----------------
__global__ __launch_bounds__(256) void k_clear(Prm p) {
  int t = blockIdx.x * 256 + threadIdx.x;
  if (t < BB * NPIX / 4) reinterpret_cast<uint4*>(p.labA)[t] = make_uint4(0u, 0u, 0u, 0u);
  if (t < p.nzero4) p.zero4[t] = make_uint4(0u, 0u, 0u, 0u);
  if (t < BB * NSEG) {
    p.ymin[t] = INTMAXC; p.ymax[t] = INTMINC; p.xmin[t] = INTMAXC; p.xmax[t] = INTMINC;
  }
}

// ---------------- K1: per-pixel pass (4 px/thread, single-exp softmax) ----------------
__global__ __launch_bounds__(256) void k_pixel(Prm p) {
  int t = blockIdx.x * 256 + threadIdx.x;
  int b = t >> 17;                                 // NPIX/4 = 2^17
  int pp = (t & 131071) << 2;
  int h = pp >> 10, w = pp & 1023;
  size_t i = (size_t)b * NPIX + pp;
  const float* base = p.seg + (size_t)b * NCC * NPIX + pp;
  float4 m = *reinterpret_cast<const float4*>(base);
  float4 s = make_float4(__expf(m.x), __expf(m.y), __expf(m.z), __expf(m.w));
  int4 am = make_int4(0, 0, 0, 0);
  #pragma unroll
  for (int c = 1; c < NCC; ++c) {
    float4 x = *reinterpret_cast<const float4*>(base + (size_t)c * NPIX);
    s.x += __expf(x.x); if (x.x > m.x) { m.x = x.x; am.x = c; }
    s.y += __expf(x.y); if (x.y > m.y) { m.y = x.y; am.y = c; }
    s.z += __expf(x.z); if (x.z > m.z) { m.z = x.z; am.z = c; }
    s.w += __expf(x.w); if (x.w > m.w) { m.w = x.w; am.w = c; }
  }
  *reinterpret_cast<float4*>(p.out_segmap + i) =
      make_float4((float)am.x, (float)am.y, (float)am.z, (float)am.w);
  *reinterpret_cast<uchar4*>(p.segc + i) =
      make_uchar4((unsigned char)am.x, (unsigned char)am.y, (unsigned char)am.z, (unsigned char)am.w);
  *reinterpret_cast<float4*>(p.pinv + i) =
      make_float4(1.f / s.x, 1.f / s.y, 1.f / s.z, 1.f / s.w);

  const float* c0 = p.cr + (size_t)b * 2 * NPIX + pp;
  float4 r0 = *reinterpret_cast<const float4*>(c0);
  float4 r1 = *reinterpret_cast<const float4*>(c0 + NPIX);
  float crx[4] = {r0.x, r0.y, r0.z, r0.w};
  float cry[4] = {r1.x, r1.y, r1.z, r1.w};
  int amA[4] = {am.x, am.y, am.z, am.w};
  int tgt[4];
  #pragma unroll
  for (int q = 0; q < 4; ++q) {
    tgt[q] = -1;
    if (amA[q] >= 24) {                            // "things": class in (23.99,33]
      float ccx = (float)(w + q + 1) - crx[q];
      float ccy = (float)(h + 1) - cry[q];
      float rx = rintf(ccx), ry = rintf(ccy);      // jnp.round (half-to-even)
      if (rx >= 0.f && ry >= 0.f && rx < (float)WW && ry < (float)HH)
        tgt[q] = (int)ry * WW + (int)rx;
    }
  }
  int lane = threadIdx.x & 63;
  uint32_t* vb = (uint32_t*)p.labA + (size_t)b * NPIX;
  #pragma unroll
  for (int q = 0; q < 4; ++q) {                    // wave-aggregated vote atomics
    int tq = tgt[q];
    unsigned long long act = __ballot(tq >= 0);
    while (act) {
      int leader = __ffsll(act) - 1;
      int tl = __shfl(tq, leader);
      unsigned long long mt = __ballot(tq == tl);
      if (lane == leader) atomicAdd(&vb[tl], (uint32_t)__popcll(mt & act));
      act &= ~mt;
    }
  }
}

// ---------------- K2: 7x7 NMS (4 px/thread), collect candidates ----------------
__global__ __launch_bounds__(256) void k_nms(Prm p) {
  int t = blockIdx.x * 256 + threadIdx.x;
  int b = t >> 17;
  int pp = (t & 131071) << 2;
  int h = pp >> 10, w0 = pp & 1023;
  const uint32_t* vb = (const uint32_t*)p.labA + (size_t)b * NPIX;
  uint4 v4 = *reinterpret_cast<const uint4*>(vb + pp);
  uint32_t vv[4] = {v4.x, v4.y, v4.z, v4.w};
  #pragma unroll
  for (int q = 0; q < 4; ++q) {
    uint32_t v = vv[q];
    if (v <= 50u) continue;                        // nms > 50.0 <=> count >= 51
    int w = w0 + q;
    bool peak = true;
    for (int dy = -3; dy <= 3 && peak; ++dy) {
      int yy = h + dy; if (yy < 0 || yy >= HH) continue;
      for (int dx = -3; dx <= 3; ++dx) {
        int xx = w + dx; if (xx < 0 || xx >= WW) continue;
        if (vb[yy * WW + xx] > v) { peak = false; break; }   // strict >
      }
    }
    if (!peak) continue;
    uint32_t pos = atomicAdd(&p.cand_cnt[b], 1u);
    if (pos < CAP) {
      p.cand_val[b * CAP + pos] = v;
      p.cand_idx[b * CAP + pos] = (uint32_t)((h + PADK) * WPAD + (w + PADK));  // PADDED
    }
  }
}

// ---------------- per-block redundant top-200 (lax.top_k tie order) ----------------
__device__ __forceinline__ int block_topk(const Prm& p, int b,
    unsigned long long* keysS, float* osx, float* osy) {
  int n = (int)p.cand_cnt[b]; if (n > CAP) n = CAP;
  const uint32_t* cv = p.cand_val + b * CAP;
  const uint32_t* ci = p.cand_idx + b * CAP;
  bool stg = (n <= KSTG);
  if (stg)
    for (int j = threadIdx.x; j < n; j += 256)
      keysS[j] = ((unsigned long long)cv[j] << 20) | (unsigned long long)(0xFFFFFu - ci[j]);
  __syncthreads();
  for (int i = threadIdx.x; i < n; i += 256) {
    unsigned long long ki = ((unsigned long long)cv[i] << 20) | (unsigned long long)(0xFFFFFu - ci[i]);
    int r = 0;
    if (stg) { for (int j = 0; j < n; ++j) r += (keysS[j] > ki) ? 1 : 0; }
    else {
      for (int j = 0; j < n; ++j) {
        unsigned long long kj = ((unsigned long long)cv[j] << 20) | (unsigned long long)(0xFFFFFu - ci[j]);
        r += (kj > ki) ? 1 : 0;                    // value desc, index asc (keys unique)
      }
    }
    if (r < TOPK) {
      uint32_t idx = ci[i];
      osx[r] = (float)(idx % WPAD);
      osy[r] = (float)(idx / WPAD);
    }
  }
  __syncthreads();
  return (n < TOPK) ? n : TOPK;
}

// ballot-scan compaction of good slots into distinct arrays; returns count.
__device__ __forceinline__ int block_compact(int good, const float* osx, const float* osy,
    float* dxs, float* dys, int* wsumS) {
  int lane = threadIdx.x & 63, wv = threadIdx.x >> 6;
  unsigned long long mask = __ballot(good);
  if (lane == 0) wsumS[wv] = (int)__popcll(mask);
  __syncthreads();
  int off = 0;
  #pragma unroll
  for (int t = 0; t < 4; ++t) off += (t < wv) ? wsumS[t] : 0;
  int total = wsumS[0] + wsumS[1] + wsumS[2] + wsumS[3];
  if (good) {
    int pos = off + (int)__popcll(mask & ((1ull << lane) - 1ull));
    dxs[pos] = osx[threadIdx.x]; dys[pos] = osy[threadIdx.x];
  }
  __syncthreads();
  return total;
}

// ---------------- per-wave conservative center prune ----------------
__device__ __forceinline__ int prune_centers(int n, const float* __restrict__ sxs,
    const float* __restrict__ sys, float minx, float maxx, float miny, float maxy,
    short* __restrict__ clist, int lane) {
  #pragma unroll
  for (int o = 32; o; o >>= 1) {
    minx = fminf(minx, __shfl_xor(minx, o));
    maxx = fmaxf(maxx, __shfl_xor(maxx, o));
    miny = fminf(miny, __shfl_xor(miny, o));
    maxy = fmaxf(maxy, __shfl_xor(maxy, o));
  }
  float cx0 = 0.5f * (minx + maxx), rx = 0.5f * (maxx - minx) + 0.5f;
  float cy0 = 0.5f * (miny + maxy), ry = 0.5f * (maxy - miny) + 0.5f;
  float lo[4];
  float ub = 3.4e38f;
  #pragma unroll
  for (int c = 0; c < 4; ++c) {
    int k = c * 64 + lane;
    float l = 3.4e38f;
    if (k < n) {
      float dx = fabsf(sxs[k] - cx0), dy = fabsf(sys[k] - cy0);
      float hx = dx + rx, hy = dy + ry;
      ub = fminf(ub, hx * hx + hy * hy);
      float lx = fmaxf(dx - rx, 0.f), ly = fmaxf(dy - ry, 0.f);
      l = lx * lx + ly * ly;
    }
    lo[c] = l;
  }
  #pragma unroll
  for (int o = 32; o; o >>= 1) ub = fminf(ub, __shfl_xor(ub, o));
  ub += 1.0f;
  int m = 0;
  unsigned long long lmlt = (1ull << lane) - 1ull;
  #pragma unroll
  for (int c = 0; c < 4; ++c) {                    // chunk-major => ascending k
    int k = c * 64 + lane;
    bool keep = (k < n) && (lo[c] <= ub);
    unsigned long long msk = __ballot(keep);
    if (keep) clist[m + (int)__popcll(msk & lmlt)] = (short)k;
    m += (int)__popcll(msk);
  }
  return m;
}

// exact argmin over pruned list (ascending original k, strict <), no-FMA math
__device__ __forceinline__ void assign4_exact(int m, const short* __restrict__ clist,
    const float* __restrict__ sxs, const float* __restrict__ sys,
    const float* ccx, const float* ccy, const unsigned char* cls, int* l) {
  float bd[4] = {3.4e38f, 3.4e38f, 3.4e38f, 3.4e38f};
  int bk[4] = {0, 0, 0, 0};
  for (int j = 0; j < m; ++j) {
    int k = (int)clist[j];
    float cxk = sxs[k], cyk = sys[k];
    #pragma unroll
    for (int q = 0; q < 4; ++q) {
      float dx = ccx[q] - cxk, dy = ccy[q] - cyk;
      float d = __fadd_rn(__fmul_rn(dx, dx), __fmul_rn(dy, dy));
      if (d < bd[q]) { bd[q] = d; bk[q] = k; }
    }
  }
  #pragma unroll
  for (int q = 0; q < 4; ++q) l[q] = (cls[q] >= 24) ? bk[q] + 1 : 0;
}

// shared assign body
__device__ __forceinline__ void assign_body(const Prm& p, int b, int h, int n,
    const float* sxs, const float* sys, short* clist_wv,
    const uchar4 sc4, const float4 r0, const float4 r1, int* l) {
  int w = threadIdx.x * 4;
  float ccx[4], ccy[4];
  #pragma unroll
  for (int q = 0; q < 4; ++q) {
    ccx[q] = (float)(w + q + 1) - ((const float*)&r0)[q];
    ccy[q] = (float)(h + 1) - ((const float*)&r1)[q];
  }
  float mnx = fminf(fminf(ccx[0], ccx[1]), fminf(ccx[2], ccx[3]));
  float mxx = fmaxf(fmaxf(ccx[0], ccx[1]), fmaxf(ccx[2], ccx[3]));
  float mny = fminf(fminf(ccy[0], ccy[1]), fminf(ccy[2], ccy[3]));
  float mxy = fmaxf(fmaxf(ccy[0], ccy[1]), fmaxf(ccy[2], ccy[3]));
  int lane = threadIdx.x & 63;
  int m = prune_centers(n, sxs, sys, mnx, mxx, mny, mxy, clist_wv, lane);
  unsigned char cls[4] = {sc4.x, sc4.y, sc4.z, sc4.w};
  assign4_exact(m, clist_wv, sxs, sys, ccx, ccy, cls, l);
}

// ---------------- K3: [topk] + assign0 + count/bbox (one row per block) ----------------
__global__ __launch_bounds__(256) void k_assign0(Prm p) {
  int b = blockIdx.y, h = blockIdx.x;
  __shared__ float sxs[TOPK], sys[TOPK];
  __shared__ short clists[4][TOPK];
  __shared__ uint32_t sc[NSEG];
  __shared__ int sx0[NSEG], sx1[NSEG];
  __shared__ unsigned long long keysS[KSTG];
  for (int j = threadIdx.x; j < NSEG; j += 256) { sc[j] = 0; sx0[j] = INTMAXC; sx1[j] = INTMINC; }
  int n = block_topk(p, b, keysS, sxs, sys);       // full top-k list, label k+1
  int w = threadIdx.x * 4;
  size_t i = (size_t)b * NPIX + h * WW + w;
  const float* c0 = p.cr + (size_t)b * 2 * NPIX + h * WW + w;
  uchar4 sc4 = *reinterpret_cast<const uchar4*>(p.segc + i);
  float4 r0 = *reinterpret_cast<const float4*>(c0);
  float4 r1 = *reinterpret_cast<const float4*>(c0 + NPIX);
  int l[4];
  if (n == 0) { l[0] = l[1] = l[2] = l[3] = 0; }   // any_c false -> lab0 = 0
  else assign_body(p, b, h, n, sxs, sys, clists[threadIdx.x >> 6], sc4, r0, r1, l);
  *reinterpret_cast<int4*>(p.labA + i) = make_int4(l[0], l[1], l[2], l[3]);
  int cur = -1; uint32_t rc = 0; int rx0 = 0, rx1 = 0;
  #pragma unroll
  for (int q = 0; q < 4; ++q) {                    // run-merged LDS atomics (skip label 0)
    int lq = l[q], x = w + q;
    if (lq == cur) { rc++; rx1 = x; }
    else {
      if (cur > 0) { atomicAdd(&sc[cur], rc); atomicMin(&sx0[cur], rx0); atomicMax(&sx1[cur], rx1); }
      cur = lq; rc = 1; rx0 = rx1 = x;
    }
  }
  if (cur > 0) { atomicAdd(&sc[cur], rc); atomicMin(&sx0[cur], rx0); atomicMax(&sx1[cur], rx1); }
  __syncthreads();
  for (int j = threadIdx.x; j < NSEG; j += 256) {
    if (sc[j]) {
      atomicAdd(&p.cnt0[b * NSEG + j], sc[j]);
      atomicMin(&p.ymin[b * NSEG + j], h); atomicMax(&p.ymax[b * NSEG + j], h);
      atomicMin(&p.xmin[b * NSEG + j], sx0[j]); atomicMax(&p.xmax[b * NSEG + j], sx1[j]);
    }
  }
}

// ---------------- K4: [topk + build1] + assign1 + count/cr-sums ----------------
__global__ __launch_bounds__(256) void k_assign1(Prm p) {
  int b = blockIdx.y, h = blockIdx.x;
  __shared__ float osx[TOPK], osy[TOPK];           // original slot coords
  __shared__ float sxs[TOPK], sys[TOPK];           // compacted good list
  __shared__ short clists[4][TOPK];
  __shared__ uint32_t sc[NSEG];
  __shared__ unsigned long long ssx[NSEG], ssy[NSEG];
  __shared__ unsigned long long keysS[KSTG];
  __shared__ int wsumS[4];
  for (int j = threadIdx.x; j < NSEG; j += 256) { sc[j] = 0; ssx[j] = 0; ssy[j] = 0; }
  block_topk(p, b, keysS, osx, osy);
  int k = threadIdx.x;
  int good = 0;
  if (k < TOPK) {                                  // bbox-ratio pruning (exact ints)
    uint32_t c = p.cnt0[b * NSEG + k + 1];
    if (c > 0) {
      int j = b * NSEG + k + 1;
      float area = (float)((p.ymax[j] - p.ymin[j] + 1) * (p.xmax[j] - p.xmin[j] + 1));
      float ratio = (float)c / area;               // same IEEE div as reference
      good = (ratio > 0.3f) ? 1 : 0;
    }
  }
  int n = block_compact(good, osx, osy, sxs, sys, wsumS);
  int w = threadIdx.x * 4;
  size_t i = (size_t)b * NPIX + h * WW + w;
  const float* c0 = p.cr + (size_t)b * 2 * NPIX + h * WW + w;
  uchar4 sc4 = *reinterpret_cast<const uchar4*>(p.segc + i);
  float4 r0 = *reinterpret_cast<const float4*>(c0);
  float4 r1 = *reinterpret_cast<const float4*>(c0 + NPIX);
  int l[4];
  if (n == 0) { int4 f = *reinterpret_cast<const int4*>(p.labA + i); l[0]=f.x; l[1]=f.y; l[2]=f.z; l[3]=f.w; }
  else assign_body(p, b, h, n, sxs, sys, clists[threadIdx.x >> 6], sc4, r0, r1, l);
  *reinterpret_cast<int4*>(p.labB + i) = make_int4(l[0], l[1], l[2], l[3]);
  float crx[4] = {r0.x, r0.y, r0.z, r0.w};
  float cry[4] = {r1.x, r1.y, r1.z, r1.w};
  int cur = -1; uint32_t rc = 0; long long ax = 0, ay = 0;
  #pragma unroll
  for (int q = 0; q < 4; ++q) {
    int lq = l[q];
    long long qx = __double2ll_rn((double)crx[q] * 1048576.0);   // 2^20 fixed-point
    long long qy = __double2ll_rn((double)cry[q] * 1048576.0);
    if (lq == cur) { rc++; ax += qx; ay += qy; }
    else {
      if (cur > 0) { atomicAdd(&sc[cur], rc);
                     atomicAdd(&ssx[cur], (unsigned long long)ax);
                     atomicAdd(&ssy[cur], (unsigned long long)ay); }
      cur = lq; rc = 1; ax = qx; ay = qy;
    }
  }
  if (cur > 0) { atomicAdd(&sc[cur], rc);
                 atomicAdd(&ssx[cur], (unsigned long long)ax);
                 atomicAdd(&ssy[cur], (unsigned long long)ay); }
  __syncthreads();
  for (int j = threadIdx.x; j < NSEG; j += 256) {
    if (sc[j]) {
      atomicAdd(&p.cnt2[b * NSEG + j], sc[j]);
      atomicAdd((unsigned long long*)&p.sxq[b * NSEG + j], ssx[j]);
      atomicAdd((unsigned long long*)&p.syq[b * NSEG + j], ssy[j]);
    }
  }
}

// ---------------- K5: [topk + build2] + assign2 + final + histogram ----------------
__global__ __launch_bounds__(256) void k_assign2(Prm p) {
  int b = blockIdx.y, h = blockIdx.x;
  __shared__ float osx[TOPK], osy[TOPK];
  __shared__ float sxs[TOPK], sys[TOPK];
  __shared__ short clists[4][TOPK];
  __shared__ uint32_t sh[NSEG * NCC];
  __shared__ unsigned long long keysS[KSTG];
  __shared__ int wsumS[4];
  for (int j = threadIdx.x; j < NSEG * NCC; j += 256) sh[j] = 0;
  block_topk(p, b, keysS, osx, osy);
  int k = threadIdx.x;
  int good = 0;
  if (k < TOPK) {                                  // mean pruning (COMPACT-space stats)
    uint32_t c = p.cnt2[b * NSEG + k + 1];
    if (c > 0) {
      double inv = 1.0 / (double)c;
      double mx = ((double)p.sxq[b * NSEG + k + 1] * (1.0 / 1048576.0)) * inv;
      double my = ((double)p.syq[b * NSEG + k + 1] * (1.0 / 1048576.0)) * inv;
      good = (fabs(mx) < 10.0 && fabs(my) < 10.0) ? 1 : 0;
    }
  }
  int n = block_compact(good, osx, osy, sxs, sys, wsumS);  // ORIGINAL sorted coords
  int w = threadIdx.x * 4;
  size_t i = (size_t)b * NPIX + h * WW + w;
  const float* c0 = p.cr + (size_t)b * 2 * NPIX + h * WW + w;
  uchar4 sc4 = *reinterpret_cast<const uchar4*>(p.segc + i);
  float4 r0 = *reinterpret_cast<const float4*>(c0);
  float4 r1 = *reinterpret_cast<const float4*>(c0 + NPIX);
  int l[4];
  if (n == 0) { int4 f = *reinterpret_cast<const int4*>(p.labB + i); l[0]=f.x; l[1]=f.y; l[2]=f.z; l[3]=f.w; }
  else assign_body(p, b, h, n, sxs, sys, clists[threadIdx.x >> 6], sc4, r0, r1, l);
  *reinterpret_cast<int4*>(p.labA + i) = make_int4(l[0], l[1], l[2], l[3]);
  *reinterpret_cast<float4*>(p.out_final + i) =
      make_float4((float)l[0], (float)l[1], (float)l[2], (float)l[3]);
  unsigned char cls[4] = {sc4.x, sc4.y, sc4.z, sc4.w};
  int curk = -1; uint32_t rc = 0;
  #pragma unroll
  for (int q = 0; q < 4; ++q) {                    // run-merged hist atomics
    int key = l[q] * NCC + (int)cls[q];
    if (key == curk) { rc++; }
    else { if (curk >= 0) atomicAdd(&sh[curk], rc); curk = key; rc = 1; }
  }
  if (curk >= 0) atomicAdd(&sh[curk], rc);
  __syncthreads();
  for (int j = threadIdx.x; j < NSEG * NCC; j += 256)
    if (sh[j]) atomicAdd(&p.hist[(size_t)b * NSEG * NCC + j], sh[j]);
}

// ---------------- K6: [mode] + prob-sum per label ----------------
__global__ __launch_bounds__(256) void k_sg(Prm p) {
  int b = blockIdx.y;
  __shared__ unsigned long long ss[NSEG];
  __shared__ int icS[NSEG];
  for (int j = threadIdx.x; j < NSEG; j += 256) {
    const uint32_t* hr = p.hist + ((size_t)b * NSEG + j) * NCC;
    uint32_t bv = hr[0], ssum = hr[0]; int bc = 0;
    #pragma unroll
    for (int c = 1; c < NCC; ++c) {
      uint32_t v = hr[c]; ssum += v;
      if (v > bv) { bv = v; bc = c; }              // first-max tie-break
    }
    icS[j] = bc;
    ss[j] = 0;
    if (blockIdx.x == 0) {                         // single writer per batch
      p.out_instc[b * NSEG + j] = (float)bc;
      p.out_cntf[b * NSEG + j] = (float)ssum;
    }
  }
  __syncthreads();
  int pp = (blockIdx.x * 256 + threadIdx.x) * 4;
  size_t i = (size_t)b * NPIX + pp;
  int4 l4 = *reinterpret_cast<const int4*>(p.labA + i);
  float4 iv = *reinterpret_cast<const float4*>(p.pinv + i);
  const float* sb = p.seg + (size_t)b * NCC * NPIX + pp;
  int lA[4] = {l4.x, l4.y, l4.z, l4.w};
  float ivA[4] = {iv.x, iv.y, iv.z, iv.w};
  int cur = -1; long long acc = 0;                 // label 0 IS included here
  #pragma unroll
  for (int q = 0; q < 4; ++q) {
    int lq = lA[q];
    int c = icS[lq];
    float x = sb[(size_t)c * NPIX + q];
    float pr = __expf(x) * ivA[q];                 // == exp(x - m)/sum(exp(x - m))
    long long qv = __double2ll_rn((double)pr * 4294967296.0);   // 2^32 fixed-point
    if (lq == cur) acc += qv;
    else { if (cur >= 0) atomicAdd(&ss[cur], (unsigned long long)acc); cur = lq; acc = qv; }
  }
  if (cur >= 0) atomicAdd(&ss[cur], (unsigned long long)acc);
  __syncthreads();
  for (int j = threadIdx.x; j < NSEG; j += 256)
    if (ss[j]) atomicAdd((unsigned long long*)&p.Ssel[b * NSEG + j], ss[j]);
}

// ---------------- K7: seg_prob = Ssel / max(cntf,1) ----------------
__global__ void k_prob(Prm p) {
  int i = blockIdx.x * blockDim.x + threadIdx.x;
  if (i >= BB * NSEG) return;
  double s = (double)p.Ssel[i] * (1.0 / 4294967296.0);
  float c = p.out_cntf[i];
  p.out_prob[i] = (float)(s / (double)fmaxf(c, 1.0f));
}

extern "C" void kernel_launch(void* const* d_in, const int* in_sizes, int n_in,
                              void* d_out, int out_size, void* d_ws, size_t ws_size,
                              hipStream_t stream) {
  float* out = (float*)d_out;
  Prm p;
  p.seg = (const float*)d_in[0];
  p.cr  = (const float*)d_in[2];
  p.out_final  = out;
  p.out_segmap = out + (size_t)BB * NPIX;
  p.out_instc  = out + (size_t)2 * BB * NPIX;
  p.out_prob   = p.out_instc + BB * NSEG;
  p.out_cntf   = p.out_prob + BB * NSEG;

  char* ws = (char*)d_ws;
  size_t off = 0;
  auto take = [&](size_t n) { size_t o = off; off += (n + 255) & ~(size_t)255; return o; };

  p.labA = (int32_t*)(ws + take((size_t)BB * NPIX * 4));  // votes -> lab0 -> final
  p.labB = (int32_t*)(ws + take((size_t)BB * NPIX * 4));  // lab1
  p.pinv = (float*)(ws + take((size_t)BB * NPIX * 4));
  p.segc = (uint8_t*)(ws + take((size_t)BB * NPIX));
  p.ymin = (int*)(ws + take(BB * NSEG * 4));               // INTMAX/MIN init (outside zero span)
  p.ymax = (int*)(ws + take(BB * NSEG * 4));
  p.xmin = (int*)(ws + take(BB * NSEG * 4));
  p.xmax = (int*)(ws + take(BB * NSEG * 4));

  size_t zero_begin = off;
  p.cand_cnt = (uint32_t*)(ws + take(BB * 4));
  p.cand_val = (uint32_t*)(ws + take((size_t)BB * CAP * 4));
  p.cand_idx = (uint32_t*)(ws + take((size_t)BB * CAP * 4));
  p.cnt0 = (uint32_t*)(ws + take(BB * NSEG * 4));
  p.cnt2 = (uint32_t*)(ws + take(BB * NSEG * 4));
  p.sxq = (long long*)(ws + take(BB * NSEG * 8));
  p.syq = (long long*)(ws + take(BB * NSEG * 8));
  p.hist = (uint32_t*)(ws + take((size_t)BB * NSEG * NCC * 4));
  p.Ssel = (long long*)(ws + take(BB * NSEG * 8));
  size_t zero_end = off;

  if (ws_size < off) return;  // workspace too small -> fail visibly

  p.zero4 = (uint4*)(ws + zero_begin);
  p.nzero4 = (int)((zero_end - zero_begin) / 16);  // 256-aligned span

  dim3 rgrid(HH, BB);
  k_clear<<<BB * NPIX / 4 / 256, 256, 0, stream>>>(p);
  k_pixel<<<BB * NPIX / 4 / 256, 256, 0, stream>>>(p);
  k_nms<<<BB * NPIX / 4 / 256, 256, 0, stream>>>(p);
  k_assign0<<<rgrid, 256, 0, stream>>>(p);                 // + topk prologue
  // BISECT: assign1 twice. Rewrites identical labB; doubles cnt2/sxq/syq which
  // is exactly invariant downstream ((2sx)*(1/(2c)) == sx*(1/c) in IEEE).
  k_assign1<<<rgrid, 256, 0, stream>>>(p);
  k_assign1<<<rgrid, 256, 0, stream>>>(p);
  k_assign2<<<rgrid, 256, 0, stream>>>(p);                 // + topk/build2 prologue
  k_sg<<<dim3(NPIX / 1024, BB), 256, 0, stream>>>(p);      // + mode prologue
  k_prob<<<(BB * NSEG + 255) / 256, 256, 0, stream>>>(p);
}

// Round 13
// 113.065 us; speedup vs baseline: 2.1727x; 1.2790x over previous
//
#include <hip/hip_runtime.h>
#include <stdint.h>

#define HH   512
#define WW   1024
#define BB   2
#define NCC  34
#define PADK 7
#define TOPK 200
#define NSEG (TOPK + 1)
#define WPAD (WW + 2 * PADK)   // 1038
#define NPIX (HH * WW)         // 524288
#define CAP  12288
#define KSTG 1024              // LDS staging capacity for topk keys
#define ATH  512               // assign kernels: 512 threads, 2 rows/block
#define INTMAXC  0x7FFFFFFF
#define INTMINC  (-0x7FFFFFFF - 1)

struct Prm {
  const float* seg; const float* cr;
  float* out_final; float* out_segmap; float* out_instc; float* out_prob; float* out_cntf;
  int32_t* labA; int32_t* labB; float* pinv; uint8_t* segc;
  int* ymin; int* ymax; int* xmin; int* xmax;
  uint4* zero4; int nzero4;
  uint32_t* cand_cnt; uint32_t* cand_val; uint32_t* cand_idx;
  uint32_t* cnt0; uint32_t* cnt2; long long* sxq; long long* syq;
  uint32_t* hist; long long* Ssel;
};

// ---------------- K0: clear votes + accumulators, init min/max ----------------
__global__ __launch_bounds__(256) void k_clear(Prm p) {
  int t = blockIdx.x * 256 + threadIdx.x;
  if (t < BB * NPIX / 4) reinterpret_cast<uint4*>(p.labA)[t] = make_uint4(0u, 0u, 0u, 0u);
  if (t < p.nzero4) p.zero4[t] = make_uint4(0u, 0u, 0u, 0u);
  if (t < BB * NSEG) {
    p.ymin[t] = INTMAXC; p.ymax[t] = INTMINC; p.xmin[t] = INTMAXC; p.xmax[t] = INTMINC;
  }
}

// ---------------- K1: per-pixel pass (4 px/thread, single-exp softmax) ----------------
// pinv = 1/sum(exp(x_j)); seg_prob later = exp(x)*pinv (2% tol path).
// Exact argmax (strict >, first max) and exact rint vote math. HBM-bound (~23us).
__global__ __launch_bounds__(256) void k_pixel(Prm p) {
  int t = blockIdx.x * 256 + threadIdx.x;
  int b = t >> 17;                                 // NPIX/4 = 2^17
  int pp = (t & 131071) << 2;
  int h = pp >> 10, w = pp & 1023;
  size_t i = (size_t)b * NPIX + pp;
  const float* base = p.seg + (size_t)b * NCC * NPIX + pp;
  float4 m = *reinterpret_cast<const float4*>(base);
  float4 s = make_float4(__expf(m.x), __expf(m.y), __expf(m.z), __expf(m.w));
  int4 am = make_int4(0, 0, 0, 0);
  #pragma unroll
  for (int c = 1; c < NCC; ++c) {
    float4 x = *reinterpret_cast<const float4*>(base + (size_t)c * NPIX);
    s.x += __expf(x.x); if (x.x > m.x) { m.x = x.x; am.x = c; }
    s.y += __expf(x.y); if (x.y > m.y) { m.y = x.y; am.y = c; }
    s.z += __expf(x.z); if (x.z > m.z) { m.z = x.z; am.z = c; }
    s.w += __expf(x.w); if (x.w > m.w) { m.w = x.w; am.w = c; }
  }
  *reinterpret_cast<float4*>(p.out_segmap + i) =
      make_float4((float)am.x, (float)am.y, (float)am.z, (float)am.w);
  *reinterpret_cast<uchar4*>(p.segc + i) =
      make_uchar4((unsigned char)am.x, (unsigned char)am.y, (unsigned char)am.z, (unsigned char)am.w);
  *reinterpret_cast<float4*>(p.pinv + i) =
      make_float4(1.f / s.x, 1.f / s.y, 1.f / s.z, 1.f / s.w);

  const float* c0 = p.cr + (size_t)b * 2 * NPIX + pp;
  float4 r0 = *reinterpret_cast<const float4*>(c0);
  float4 r1 = *reinterpret_cast<const float4*>(c0 + NPIX);
  float crx[4] = {r0.x, r0.y, r0.z, r0.w};
  float cry[4] = {r1.x, r1.y, r1.z, r1.w};
  int amA[4] = {am.x, am.y, am.z, am.w};
  int tgt[4];
  #pragma unroll
  for (int q = 0; q < 4; ++q) {
    tgt[q] = -1;
    if (amA[q] >= 24) {                            // "things": class in (23.99,33]
      float ccx = (float)(w + q + 1) - crx[q];
      float ccy = (float)(h + 1) - cry[q];
      float rx = rintf(ccx), ry = rintf(ccy);      // jnp.round (half-to-even)
      if (rx >= 0.f && ry >= 0.f && rx < (float)WW && ry < (float)HH)
        tgt[q] = (int)ry * WW + (int)rx;
    }
  }
  int lane = threadIdx.x & 63;
  uint32_t* vb = (uint32_t*)p.labA + (size_t)b * NPIX;
  #pragma unroll
  for (int q = 0; q < 4; ++q) {                    // wave-aggregated vote atomics
    int tq = tgt[q];
    unsigned long long act = __ballot(tq >= 0);
    while (act) {
      int leader = __ffsll(act) - 1;
      int tl = __shfl(tq, leader);
      unsigned long long mt = __ballot(tq == tl);
      if (lane == leader) atomicAdd(&vb[tl], (uint32_t)__popcll(mt & act));
      act &= ~mt;
    }
  }
}

// ---------------- K2: 7x7 NMS (4 px/thread), collect candidates ----------------
__global__ __launch_bounds__(256) void k_nms(Prm p) {
  int t = blockIdx.x * 256 + threadIdx.x;
  int b = t >> 17;
  int pp = (t & 131071) << 2;
  int h = pp >> 10, w0 = pp & 1023;
  const uint32_t* vb = (const uint32_t*)p.labA + (size_t)b * NPIX;
  uint4 v4 = *reinterpret_cast<const uint4*>(vb + pp);
  uint32_t vv[4] = {v4.x, v4.y, v4.z, v4.w};
  #pragma unroll
  for (int q = 0; q < 4; ++q) {
    uint32_t v = vv[q];
    if (v <= 50u) continue;                        // nms > 50.0 <=> count >= 51
    int w = w0 + q;
    bool peak = true;
    for (int dy = -3; dy <= 3 && peak; ++dy) {
      int yy = h + dy; if (yy < 0 || yy >= HH) continue;
      for (int dx = -3; dx <= 3; ++dx) {
        int xx = w + dx; if (xx < 0 || xx >= WW) continue;
        if (vb[yy * WW + xx] > v) { peak = false; break; }   // strict >
      }
    }
    if (!peak) continue;
    uint32_t pos = atomicAdd(&p.cand_cnt[b], 1u);
    if (pos < CAP) {
      p.cand_val[b * CAP + pos] = v;
      p.cand_idx[b * CAP + pos] = (uint32_t)((h + PADK) * WPAD + (w + PADK));  // PADDED
    }
  }
}

// ---------------- per-block redundant top-200 (lax.top_k tie order) ----------------
// Candidates L2-resident; every block recomputes the identical list.
__device__ __forceinline__ int block_topk(const Prm& p, int b,
    unsigned long long* keysS, float* osx, float* osy) {
  int n = (int)p.cand_cnt[b]; if (n > CAP) n = CAP;
  const uint32_t* cv = p.cand_val + b * CAP;
  const uint32_t* ci = p.cand_idx + b * CAP;
  bool stg = (n <= KSTG);
  if (stg)
    for (int j = threadIdx.x; j < n; j += ATH)
      keysS[j] = ((unsigned long long)cv[j] << 20) | (unsigned long long)(0xFFFFFu - ci[j]);
  __syncthreads();
  for (int i = threadIdx.x; i < n; i += ATH) {
    unsigned long long ki = ((unsigned long long)cv[i] << 20) | (unsigned long long)(0xFFFFFu - ci[i]);
    int r = 0;
    if (stg) { for (int j = 0; j < n; ++j) r += (keysS[j] > ki) ? 1 : 0; }
    else {
      for (int j = 0; j < n; ++j) {
        unsigned long long kj = ((unsigned long long)cv[j] << 20) | (unsigned long long)(0xFFFFFu - ci[j]);
        r += (kj > ki) ? 1 : 0;                    // value desc, index asc (keys unique)
      }
    }
    if (r < TOPK) {
      uint32_t idx = ci[i];
      osx[r] = (float)(idx % WPAD);
      osy[r] = (float)(idx / WPAD);
    }
  }
  __syncthreads();
  return (n < TOPK) ? n : TOPK;
}

// ballot-scan compaction of good slots into distinct arrays; returns count. 8 waves.
__device__ __forceinline__ int block_compact(int good, const float* osx, const float* osy,
    float* dxs, float* dys, int* wsumS) {
  int lane = threadIdx.x & 63, wv = threadIdx.x >> 6;
  unsigned long long mask = __ballot(good);
  if (lane == 0) wsumS[wv] = (int)__popcll(mask);
  __syncthreads();
  int off = 0, total = 0;
  #pragma unroll
  for (int t = 0; t < ATH / 64; ++t) { off += (t < wv) ? wsumS[t] : 0; total += wsumS[t]; }
  if (good) {
    int pos = off + (int)__popcll(mask & ((1ull << lane) - 1ull));
    dxs[pos] = osx[threadIdx.x]; dys[pos] = osy[threadIdx.x];
  }
  __syncthreads();
  return total;
}

// ---------------- per-wave conservative center prune ----------------
__device__ __forceinline__ int prune_centers(int n, const float* __restrict__ sxs,
    const float* __restrict__ sys, float minx, float maxx, float miny, float maxy,
    short* __restrict__ clist, int lane) {
  #pragma unroll
  for (int o = 32; o; o >>= 1) {
    minx = fminf(minx, __shfl_xor(minx, o));
    maxx = fmaxf(maxx, __shfl_xor(maxx, o));
    miny = fminf(miny, __shfl_xor(miny, o));
    maxy = fmaxf(maxy, __shfl_xor(maxy, o));
  }
  float cx0 = 0.5f * (minx + maxx), rx = 0.5f * (maxx - minx) + 0.5f;
  float cy0 = 0.5f * (miny + maxy), ry = 0.5f * (maxy - miny) + 0.5f;
  float lo[4];
  float ub = 3.4e38f;
  #pragma unroll
  for (int c = 0; c < 4; ++c) {
    int k = c * 64 + lane;
    float l = 3.4e38f;
    if (k < n) {
      float dx = fabsf(sxs[k] - cx0), dy = fabsf(sys[k] - cy0);
      float hx = dx + rx, hy = dy + ry;
      ub = fminf(ub, hx * hx + hy * hy);
      float lx = fmaxf(dx - rx, 0.f), ly = fmaxf(dy - ry, 0.f);
      l = lx * lx + ly * ly;
    }
    lo[c] = l;
  }
  #pragma unroll
  for (int o = 32; o; o >>= 1) ub = fminf(ub, __shfl_xor(ub, o));
  ub += 1.0f;
  int m = 0;
  unsigned long long lmlt = (1ull << lane) - 1ull;
  #pragma unroll
  for (int c = 0; c < 4; ++c) {                    // chunk-major => ascending k
    int k = c * 64 + lane;
    bool keep = (k < n) && (lo[c] <= ub);
    unsigned long long msk = __ballot(keep);
    if (keep) clist[m + (int)__popcll(msk & lmlt)] = (short)k;
    m += (int)__popcll(msk);
  }
  return m;
}

// exact argmin over pruned list (ascending original k, strict <), no-FMA math
__device__ __forceinline__ void assign4_exact(int m, const short* __restrict__ clist,
    const float* __restrict__ sxs, const float* __restrict__ sys,
    const float* ccx, const float* ccy, const unsigned char* cls, int* l) {
  float bd[4] = {3.4e38f, 3.4e38f, 3.4e38f, 3.4e38f};
  int bk[4] = {0, 0, 0, 0};
  for (int j = 0; j < m; ++j) {
    int k = (int)clist[j];
    float cxk = sxs[k], cyk = sys[k];
    #pragma unroll
    for (int q = 0; q < 4; ++q) {
      float dx = ccx[q] - cxk, dy = ccy[q] - cyk;
      float d = __fadd_rn(__fmul_rn(dx, dx), __fmul_rn(dy, dy));
      if (d < bd[q]) { bd[q] = d; bk[q] = k; }
    }
  }
  #pragma unroll
  for (int q = 0; q < 4; ++q) l[q] = (cls[q] >= 24) ? bk[q] + 1 : 0;
}

// shared assign body (w, h explicit; wave spans ONE row)
__device__ __forceinline__ void assign_body(int n, const float* sxs, const float* sys,
    short* clist_wv, int w, int h,
    const uchar4 sc4, const float4 r0, const float4 r1, int* l) {
  float ccx[4], ccy[4];
  #pragma unroll
  for (int q = 0; q < 4; ++q) {
    ccx[q] = (float)(w + q + 1) - ((const float*)&r0)[q];
    ccy[q] = (float)(h + 1) - ((const float*)&r1)[q];
  }
  float mnx = fminf(fminf(ccx[0], ccx[1]), fminf(ccx[2], ccx[3]));
  float mxx = fmaxf(fmaxf(ccx[0], ccx[1]), fmaxf(ccx[2], ccx[3]));
  float mny = fminf(fminf(ccy[0], ccy[1]), fminf(ccy[2], ccy[3]));
  float mxy = fmaxf(fmaxf(ccy[0], ccy[1]), fmaxf(ccy[2], ccy[3]));
  int lane = threadIdx.x & 63;
  int m = prune_centers(n, sxs, sys, mnx, mxx, mny, mxy, clist_wv, lane);
  unsigned char cls[4] = {sc4.x, sc4.y, sc4.z, sc4.w};
  assign4_exact(m, clist_wv, sxs, sys, ccx, ccy, cls, l);
}

// ---------------- K3: [topk] + assign0 + count/bbox (TWO rows per block) ----------------
__global__ __launch_bounds__(ATH) void k_assign0(Prm p) {
  int b = blockIdx.y;
  int r = threadIdx.x >> 8;                        // 0/1: which row
  int h = (blockIdx.x << 1) | r;
  int w = (threadIdx.x & 255) * 4;
  __shared__ float sxs[TOPK], sys[TOPK];
  __shared__ short clists[ATH / 64][TOPK];
  __shared__ uint32_t sc[NSEG];
  __shared__ int sx0[NSEG], sx1[NSEG], sy0[NSEG], sy1[NSEG];
  __shared__ unsigned long long keysS[KSTG];
  for (int j = threadIdx.x; j < NSEG; j += ATH) {
    sc[j] = 0; sx0[j] = INTMAXC; sx1[j] = INTMINC; sy0[j] = INTMAXC; sy1[j] = INTMINC;
  }
  int n = block_topk(p, b, keysS, sxs, sys);       // full top-k list, label k+1
  size_t i = (size_t)b * NPIX + h * WW + w;
  const float* c0 = p.cr + (size_t)b * 2 * NPIX + h * WW + w;
  uchar4 sc4 = *reinterpret_cast<const uchar4*>(p.segc + i);
  float4 r0 = *reinterpret_cast<const float4*>(c0);
  float4 r1 = *reinterpret_cast<const float4*>(c0 + NPIX);
  int l[4];
  if (n == 0) { l[0] = l[1] = l[2] = l[3] = 0; }   // any_c false -> lab0 = 0
  else assign_body(n, sxs, sys, clists[threadIdx.x >> 6], w, h, sc4, r0, r1, l);
  *reinterpret_cast<int4*>(p.labA + i) = make_int4(l[0], l[1], l[2], l[3]);
  int cur = -1; uint32_t rc = 0; int rx0 = 0, rx1 = 0;
  #pragma unroll
  for (int q = 0; q < 4; ++q) {                    // run-merged LDS atomics (skip label 0)
    int lq = l[q], x = w + q;
    if (lq == cur) { rc++; rx1 = x; }
    else {
      if (cur > 0) { atomicAdd(&sc[cur], rc); atomicMin(&sx0[cur], rx0); atomicMax(&sx1[cur], rx1);
                     atomicMin(&sy0[cur], h); atomicMax(&sy1[cur], h); }
      cur = lq; rc = 1; rx0 = rx1 = x;
    }
  }
  if (cur > 0) { atomicAdd(&sc[cur], rc); atomicMin(&sx0[cur], rx0); atomicMax(&sx1[cur], rx1);
                 atomicMin(&sy0[cur], h); atomicMax(&sy1[cur], h); }
  __syncthreads();
  for (int j = threadIdx.x; j < NSEG; j += ATH) {
    if (sc[j]) {
      atomicAdd(&p.cnt0[b * NSEG + j], sc[j]);
      atomicMin(&p.ymin[b * NSEG + j], sy0[j]); atomicMax(&p.ymax[b * NSEG + j], sy1[j]);
      atomicMin(&p.xmin[b * NSEG + j], sx0[j]); atomicMax(&p.xmax[b * NSEG + j], sx1[j]);
    }
  }
}

// ---------------- K4: [topk + build1] + assign1 + count/cr-sums (2 rows) ----------------
__global__ __launch_bounds__(ATH) void k_assign1(Prm p) {
  int b = blockIdx.y;
  int r = threadIdx.x >> 8;
  int h = (blockIdx.x << 1) | r;
  int w = (threadIdx.x & 255) * 4;
  __shared__ float osx[TOPK], osy[TOPK];           // original slot coords
  __shared__ float sxs[TOPK], sys[TOPK];           // compacted good list
  __shared__ short clists[ATH / 64][TOPK];
  __shared__ uint32_t sc[NSEG];
  __shared__ unsigned long long ssx[NSEG], ssy[NSEG];
  __shared__ unsigned long long keysS[KSTG];
  __shared__ int wsumS[ATH / 64];
  for (int j = threadIdx.x; j < NSEG; j += ATH) { sc[j] = 0; ssx[j] = 0; ssy[j] = 0; }
  block_topk(p, b, keysS, osx, osy);
  int k = threadIdx.x;
  int good = 0;
  if (k < TOPK) {                                  // bbox-ratio pruning (exact ints)
    uint32_t c = p.cnt0[b * NSEG + k + 1];
    if (c > 0) {
      int j = b * NSEG + k + 1;
      float area = (float)((p.ymax[j] - p.ymin[j] + 1) * (p.xmax[j] - p.xmin[j] + 1));
      float ratio = (float)c / area;               // same IEEE div as reference
      good = (ratio > 0.3f) ? 1 : 0;
    }
  }
  int n = block_compact(good, osx, osy, sxs, sys, wsumS);
  size_t i = (size_t)b * NPIX + h * WW + w;
  const float* c0 = p.cr + (size_t)b * 2 * NPIX + h * WW + w;
  uchar4 sc4 = *reinterpret_cast<const uchar4*>(p.segc + i);
  float4 r0 = *reinterpret_cast<const float4*>(c0);
  float4 r1 = *reinterpret_cast<const float4*>(c0 + NPIX);
  int l[4];
  if (n == 0) { int4 f = *reinterpret_cast<const int4*>(p.labA + i); l[0]=f.x; l[1]=f.y; l[2]=f.z; l[3]=f.w; }
  else assign_body(n, sxs, sys, clists[threadIdx.x >> 6], w, h, sc4, r0, r1, l);
  *reinterpret_cast<int4*>(p.labB + i) = make_int4(l[0], l[1], l[2], l[3]);
  float crx[4] = {r0.x, r0.y, r0.z, r0.w};
  float cry[4] = {r1.x, r1.y, r1.z, r1.w};
  int cur = -1; uint32_t rc = 0; long long ax = 0, ay = 0;
  #pragma unroll
  for (int q = 0; q < 4; ++q) {
    int lq = l[q];
    long long qx = __double2ll_rn((double)crx[q] * 1048576.0);   // 2^20 fixed-point
    long long qy = __double2ll_rn((double)cry[q] * 1048576.0);
    if (lq == cur) { rc++; ax += qx; ay += qy; }
    else {
      if (cur > 0) { atomicAdd(&sc[cur], rc);
                     atomicAdd(&ssx[cur], (unsigned long long)ax);
                     atomicAdd(&ssy[cur], (unsigned long long)ay); }
      cur = lq; rc = 1; ax = qx; ay = qy;
    }
  }
  if (cur > 0) { atomicAdd(&sc[cur], rc);
                 atomicAdd(&ssx[cur], (unsigned long long)ax);
                 atomicAdd(&ssy[cur], (unsigned long long)ay); }
  __syncthreads();
  for (int j = threadIdx.x; j < NSEG; j += ATH) {
    if (sc[j]) {
      atomicAdd(&p.cnt2[b * NSEG + j], sc[j]);
      atomicAdd((unsigned long long*)&p.sxq[b * NSEG + j], ssx[j]);
      atomicAdd((unsigned long long*)&p.syq[b * NSEG + j], ssy[j]);
    }
  }
}

// ---------------- K5: [topk + build2] + assign2 + final + histogram (2 rows) ----------------
__global__ __launch_bounds__(ATH) void k_assign2(Prm p) {
  int b = blockIdx.y;
  int r = threadIdx.x >> 8;
  int h = (blockIdx.x << 1) | r;
  int w = (threadIdx.x & 255) * 4;
  __shared__ float osx[TOPK], osy[TOPK];
  __shared__ float sxs[TOPK], sys[TOPK];
  __shared__ short clists[ATH / 64][TOPK];
  __shared__ uint32_t sh[NSEG * NCC];
  __shared__ unsigned long long keysS[KSTG];
  __shared__ int wsumS[ATH / 64];
  for (int j = threadIdx.x; j < NSEG * NCC; j += ATH) sh[j] = 0;
  block_topk(p, b, keysS, osx, osy);
  int k = threadIdx.x;
  int good = 0;
  if (k < TOPK) {                                  // mean pruning (COMPACT-space stats)
    uint32_t c = p.cnt2[b * NSEG + k + 1];
    if (c > 0) {
      double inv = 1.0 / (double)c;
      double mx = ((double)p.sxq[b * NSEG + k + 1] * (1.0 / 1048576.0)) * inv;
      double my = ((double)p.syq[b * NSEG + k + 1] * (1.0 / 1048576.0)) * inv;
      good = (fabs(mx) < 10.0 && fabs(my) < 10.0) ? 1 : 0;
    }
  }
  int n = block_compact(good, osx, osy, sxs, sys, wsumS);  // ORIGINAL sorted coords
  size_t i = (size_t)b * NPIX + h * WW + w;
  const float* c0 = p.cr + (size_t)b * 2 * NPIX + h * WW + w;
  uchar4 sc4 = *reinterpret_cast<const uchar4*>(p.segc + i);
  float4 r0 = *reinterpret_cast<const float4*>(c0);
  float4 r1 = *reinterpret_cast<const float4*>(c0 + NPIX);
  int l[4];
  if (n == 0) { int4 f = *reinterpret_cast<const int4*>(p.labB + i); l[0]=f.x; l[1]=f.y; l[2]=f.z; l[3]=f.w; }
  else assign_body(n, sxs, sys, clists[threadIdx.x >> 6], w, h, sc4, r0, r1, l);
  *reinterpret_cast<int4*>(p.labA + i) = make_int4(l[0], l[1], l[2], l[3]);
  *reinterpret_cast<float4*>(p.out_final + i) =
      make_float4((float)l[0], (float)l[1], (float)l[2], (float)l[3]);
  unsigned char cls[4] = {sc4.x, sc4.y, sc4.z, sc4.w};
  int curk = -1; uint32_t rc = 0;
  #pragma unroll
  for (int q = 0; q < 4; ++q) {                    // run-merged hist atomics
    int key = l[q] * NCC + (int)cls[q];
    if (key == curk) { rc++; }
    else { if (curk >= 0) atomicAdd(&sh[curk], rc); curk = key; rc = 1; }
  }
  if (curk >= 0) atomicAdd(&sh[curk], rc);
  __syncthreads();
  for (int j = threadIdx.x; j < NSEG * NCC; j += ATH)
    if (sh[j]) atomicAdd(&p.hist[(size_t)b * NSEG * NCC + j], sh[j]);
}

// ---------------- K6: [mode] + prob-sum per label ----------------
__global__ __launch_bounds__(256) void k_sg(Prm p) {
  int b = blockIdx.y;
  __shared__ unsigned long long ss[NSEG];
  __shared__ int icS[NSEG];
  for (int j = threadIdx.x; j < NSEG; j += 256) {
    const uint32_t* hr = p.hist + ((size_t)b * NSEG + j) * NCC;
    uint32_t bv = hr[0], ssum = hr[0]; int bc = 0;
    #pragma unroll
    for (int c = 1; c < NCC; ++c) {
      uint32_t v = hr[c]; ssum += v;
      if (v > bv) { bv = v; bc = c; }              // first-max tie-break
    }
    icS[j] = bc;
    ss[j] = 0;
    if (blockIdx.x == 0) {                         // single writer per batch
      p.out_instc[b * NSEG + j] = (float)bc;
      p.out_cntf[b * NSEG + j] = (float)ssum;
    }
  }
  __syncthreads();
  int pp = (blockIdx.x * 256 + threadIdx.x) * 4;
  size_t i = (size_t)b * NPIX + pp;
  int4 l4 = *reinterpret_cast<const int4*>(p.labA + i);
  float4 iv = *reinterpret_cast<const float4*>(p.pinv + i);
  const float* sb = p.seg + (size_t)b * NCC * NPIX + pp;
  int lA[4] = {l4.x, l4.y, l4.z, l4.w};
  float ivA[4] = {iv.x, iv.y, iv.z, iv.w};
  int cur = -1; long long acc = 0;                 // label 0 IS included here
  #pragma unroll
  for (int q = 0; q < 4; ++q) {
    int lq = lA[q];
    int c = icS[lq];
    float x = sb[(size_t)c * NPIX + q];
    float pr = __expf(x) * ivA[q];                 // == exp(x - m)/sum(exp(x - m))
    long long qv = __double2ll_rn((double)pr * 4294967296.0);   // 2^32 fixed-point
    if (lq == cur) acc += qv;
    else { if (cur >= 0) atomicAdd(&ss[cur], (unsigned long long)acc); cur = lq; acc = qv; }
  }
  if (cur >= 0) atomicAdd(&ss[cur], (unsigned long long)acc);
  __syncthreads();
  for (int j = threadIdx.x; j < NSEG; j += 256)
    if (ss[j]) atomicAdd((unsigned long long*)&p.Ssel[b * NSEG + j], ss[j]);
}

// ---------------- K7: seg_prob = Ssel / max(cntf,1) ----------------
__global__ void k_prob(Prm p) {
  int i = blockIdx.x * blockDim.x + threadIdx.x;
  if (i >= BB * NSEG) return;
  double s = (double)p.Ssel[i] * (1.0 / 4294967296.0);
  float c = p.out_cntf[i];
  p.out_prob[i] = (float)(s / (double)fmaxf(c, 1.0f));
}

extern "C" void kernel_launch(void* const* d_in, const int* in_sizes, int n_in,
                              void* d_out, int out_size, void* d_ws, size_t ws_size,
                              hipStream_t stream) {
  float* out = (float*)d_out;
  Prm p;
  p.seg = (const float*)d_in[0];
  p.cr  = (const float*)d_in[2];
  p.out_final  = out;
  p.out_segmap = out + (size_t)BB * NPIX;
  p.out_instc  = out + (size_t)2 * BB * NPIX;
  p.out_prob   = p.out_instc + BB * NSEG;
  p.out_cntf   = p.out_prob + BB * NSEG;

  char* ws = (char*)d_ws;
  size_t off = 0;
  auto take = [&](size_t n) { size_t o = off; off += (n + 255) & ~(size_t)255; return o; };

  p.labA = (int32_t*)(ws + take((size_t)BB * NPIX * 4));  // votes -> lab0 -> final
  p.labB = (int32_t*)(ws + take((size_t)BB * NPIX * 4));  // lab1
  p.pinv = (float*)(ws + take((size_t)BB * NPIX * 4));
  p.segc = (uint8_t*)(ws + take((size_t)BB * NPIX));
  p.ymin = (int*)(ws + take(BB * NSEG * 4));               // INTMAX/MIN init (outside zero span)
  p.ymax = (int*)(ws + take(BB * NSEG * 4));
  p.xmin = (int*)(ws + take(BB * NSEG * 4));
  p.xmax = (int*)(ws + take(BB * NSEG * 4));

  size_t zero_begin = off;
  p.cand_cnt = (uint32_t*)(ws + take(BB * 4));
  p.cand_val = (uint32_t*)(ws + take((size_t)BB * CAP * 4));
  p.cand_idx = (uint32_t*)(ws + take((size_t)BB * CAP * 4));
  p.cnt0 = (uint32_t*)(ws + take(BB * NSEG * 4));
  p.cnt2 = (uint32_t*)(ws + take(BB * NSEG * 4));
  p.sxq = (long long*)(ws + take(BB * NSEG * 8));
  p.syq = (long long*)(ws + take(BB * NSEG * 8));
  p.hist = (uint32_t*)(ws + take((size_t)BB * NSEG * NCC * 4));
  p.Ssel = (long long*)(ws + take(BB * NSEG * 8));
  size_t zero_end = off;

  if (ws_size < off) return;  // workspace too small -> fail visibly

  p.zero4 = (uint4*)(ws + zero_begin);
  p.nzero4 = (int)((zero_end - zero_begin) / 16);  // 256-aligned span

  k_clear<<<BB * NPIX / 4 / 256, 256, 0, stream>>>(p);
  k_pixel<<<BB * NPIX / 4 / 256, 256, 0, stream>>>(p);
  k_nms<<<BB * NPIX / 4 / 256, 256, 0, stream>>>(p);
  dim3 agrid(HH / 2, BB);                          // 2 rows per block, 512 threads
  k_assign0<<<agrid, ATH, 0, stream>>>(p);                 // + topk prologue
  k_assign1<<<agrid, ATH, 0, stream>>>(p);                 // + topk/build1 prologue
  k_assign2<<<agrid, ATH, 0, stream>>>(p);                 // + topk/build2 prologue
  k_sg<<<dim3(NPIX / 1024, BB), 256, 0, stream>>>(p);      // + mode prologue
  k_prob<<<(BB * NSEG + 255) / 256, 256, 0, stream>>>(p);
}

// Round 14
// 108.513 us; speedup vs baseline: 2.2639x; 1.0420x over previous
//
#include <hip/hip_runtime.h>
#include <stdint.h>

#define HH   512
#define WW   1024
#define BB   2
#define NCC  34
#define PADK 7
#define TOPK 200
#define NSEG (TOPK + 1)
#define WPAD (WW + 2 * PADK)   // 1038
#define NPIX (HH * WW)         // 524288
#define CAP  12288
#define KSTG 1024              // LDS staging capacity for topk keys
#define ATH  1024              // assign kernels: 1024 threads, 4 rows/block
#define INTMAXC  0x7FFFFFFF
#define INTMINC  (-0x7FFFFFFF - 1)

struct Prm {
  const float* seg; const float* cr;
  float* out_final; float* out_segmap; float* out_instc; float* out_prob; float* out_cntf;
  int32_t* labA; int32_t* labB; float* pinv; uint8_t* segc;
  int* ymin; int* ymax; int* xmin; int* xmax;
  uint4* zero4; int nzero4;
  uint32_t* cand_cnt; uint32_t* cand_val; uint32_t* cand_idx;
  uint32_t* cnt0; uint32_t* cnt2; long long* sxq; long long* syq;
  uint32_t* hist; long long* Ssel;
};

// ---------------- K0: clear votes + accumulators, init min/max ----------------
__global__ __launch_bounds__(256) void k_clear(Prm p) {
  int t = blockIdx.x * 256 + threadIdx.x;
  if (t < BB * NPIX / 4) reinterpret_cast<uint4*>(p.labA)[t] = make_uint4(0u, 0u, 0u, 0u);
  if (t < p.nzero4) p.zero4[t] = make_uint4(0u, 0u, 0u, 0u);
  if (t < BB * NSEG) {
    p.ymin[t] = INTMAXC; p.ymax[t] = INTMINC; p.xmin[t] = INTMAXC; p.xmax[t] = INTMINC;
  }
}

// ---------------- K1: per-pixel pass (4 px/thread, single-exp softmax) ----------------
// pinv = 1/sum(exp(x_j)); seg_prob later = exp(x)*pinv (2% tol path).
// Exact argmax (strict >, first max) and exact rint vote math. HBM-bound (~23us).
__global__ __launch_bounds__(256) void k_pixel(Prm p) {
  int t = blockIdx.x * 256 + threadIdx.x;
  int b = t >> 17;                                 // NPIX/4 = 2^17
  int pp = (t & 131071) << 2;
  int h = pp >> 10, w = pp & 1023;
  size_t i = (size_t)b * NPIX + pp;
  const float* base = p.seg + (size_t)b * NCC * NPIX + pp;
  float4 m = *reinterpret_cast<const float4*>(base);
  float4 s = make_float4(__expf(m.x), __expf(m.y), __expf(m.z), __expf(m.w));
  int4 am = make_int4(0, 0, 0, 0);
  #pragma unroll
  for (int c = 1; c < NCC; ++c) {
    float4 x = *reinterpret_cast<const float4*>(base + (size_t)c * NPIX);
    s.x += __expf(x.x); if (x.x > m.x) { m.x = x.x; am.x = c; }
    s.y += __expf(x.y); if (x.y > m.y) { m.y = x.y; am.y = c; }
    s.z += __expf(x.z); if (x.z > m.z) { m.z = x.z; am.z = c; }
    s.w += __expf(x.w); if (x.w > m.w) { m.w = x.w; am.w = c; }
  }
  *reinterpret_cast<float4*>(p.out_segmap + i) =
      make_float4((float)am.x, (float)am.y, (float)am.z, (float)am.w);
  *reinterpret_cast<uchar4*>(p.segc + i) =
      make_uchar4((unsigned char)am.x, (unsigned char)am.y, (unsigned char)am.z, (unsigned char)am.w);
  *reinterpret_cast<float4*>(p.pinv + i) =
      make_float4(1.f / s.x, 1.f / s.y, 1.f / s.z, 1.f / s.w);

  const float* c0 = p.cr + (size_t)b * 2 * NPIX + pp;
  float4 r0 = *reinterpret_cast<const float4*>(c0);
  float4 r1 = *reinterpret_cast<const float4*>(c0 + NPIX);
  float crx[4] = {r0.x, r0.y, r0.z, r0.w};
  float cry[4] = {r1.x, r1.y, r1.z, r1.w};
  int amA[4] = {am.x, am.y, am.z, am.w};
  int tgt[4];
  #pragma unroll
  for (int q = 0; q < 4; ++q) {
    tgt[q] = -1;
    if (amA[q] >= 24) {                            // "things": class in (23.99,33]
      float ccx = (float)(w + q + 1) - crx[q];
      float ccy = (float)(h + 1) - cry[q];
      float rx = rintf(ccx), ry = rintf(ccy);      // jnp.round (half-to-even)
      if (rx >= 0.f && ry >= 0.f && rx < (float)WW && ry < (float)HH)
        tgt[q] = (int)ry * WW + (int)rx;
    }
  }
  int lane = threadIdx.x & 63;
  uint32_t* vb = (uint32_t*)p.labA + (size_t)b * NPIX;
  #pragma unroll
  for (int q = 0; q < 4; ++q) {                    // wave-aggregated vote atomics
    int tq = tgt[q];
    unsigned long long act = __ballot(tq >= 0);
    while (act) {
      int leader = __ffsll(act) - 1;
      int tl = __shfl(tq, leader);
      unsigned long long mt = __ballot(tq == tl);
      if (lane == leader) atomicAdd(&vb[tl], (uint32_t)__popcll(mt & act));
      act &= ~mt;
    }
  }
}

// ---------------- K2: 7x7 NMS (4 px/thread), collect candidates ----------------
__global__ __launch_bounds__(256) void k_nms(Prm p) {
  int t = blockIdx.x * 256 + threadIdx.x;
  int b = t >> 17;
  int pp = (t & 131071) << 2;
  int h = pp >> 10, w0 = pp & 1023;
  const uint32_t* vb = (const uint32_t*)p.labA + (size_t)b * NPIX;
  uint4 v4 = *reinterpret_cast<const uint4*>(vb + pp);
  uint32_t vv[4] = {v4.x, v4.y, v4.z, v4.w};
  #pragma unroll
  for (int q = 0; q < 4; ++q) {
    uint32_t v = vv[q];
    if (v <= 50u) continue;                        // nms > 50.0 <=> count >= 51
    int w = w0 + q;
    bool peak = true;
    for (int dy = -3; dy <= 3 && peak; ++dy) {
      int yy = h + dy; if (yy < 0 || yy >= HH) continue;
      for (int dx = -3; dx <= 3; ++dx) {
        int xx = w + dx; if (xx < 0 || xx >= WW) continue;
        if (vb[yy * WW + xx] > v) { peak = false; break; }   // strict >
      }
    }
    if (!peak) continue;
    uint32_t pos = atomicAdd(&p.cand_cnt[b], 1u);
    if (pos < CAP) {
      p.cand_val[b * CAP + pos] = v;
      p.cand_idx[b * CAP + pos] = (uint32_t)((h + PADK) * WPAD + (w + PADK));  // PADDED
    }
  }
}

// ---------------- per-block redundant top-200 (lax.top_k tie order) ----------------
// Candidates L2-resident; every block recomputes the identical list.
__device__ __forceinline__ int block_topk(const Prm& p, int b,
    unsigned long long* keysS, float* osx, float* osy) {
  int n = (int)p.cand_cnt[b]; if (n > CAP) n = CAP;
  const uint32_t* cv = p.cand_val + b * CAP;
  const uint32_t* ci = p.cand_idx + b * CAP;
  bool stg = (n <= KSTG);
  if (stg)
    for (int j = threadIdx.x; j < n; j += ATH)
      keysS[j] = ((unsigned long long)cv[j] << 20) | (unsigned long long)(0xFFFFFu - ci[j]);
  __syncthreads();
  for (int i = threadIdx.x; i < n; i += ATH) {
    unsigned long long ki = ((unsigned long long)cv[i] << 20) | (unsigned long long)(0xFFFFFu - ci[i]);
    int r = 0;
    if (stg) { for (int j = 0; j < n; ++j) r += (keysS[j] > ki) ? 1 : 0; }
    else {
      for (int j = 0; j < n; ++j) {
        unsigned long long kj = ((unsigned long long)cv[j] << 20) | (unsigned long long)(0xFFFFFu - ci[j]);
        r += (kj > ki) ? 1 : 0;                    // value desc, index asc (keys unique)
      }
    }
    if (r < TOPK) {
      uint32_t idx = ci[i];
      osx[r] = (float)(idx % WPAD);
      osy[r] = (float)(idx / WPAD);
    }
  }
  __syncthreads();
  return (n < TOPK) ? n : TOPK;
}

// ballot-scan compaction of good slots into distinct arrays; returns count. 16 waves.
__device__ __forceinline__ int block_compact(int good, const float* osx, const float* osy,
    float* dxs, float* dys, int* wsumS) {
  int lane = threadIdx.x & 63, wv = threadIdx.x >> 6;
  unsigned long long mask = __ballot(good);
  if (lane == 0) wsumS[wv] = (int)__popcll(mask);
  __syncthreads();
  int off = 0, total = 0;
  #pragma unroll
  for (int t = 0; t < ATH / 64; ++t) { off += (t < wv) ? wsumS[t] : 0; total += wsumS[t]; }
  if (good) {
    int pos = off + (int)__popcll(mask & ((1ull << lane) - 1ull));
    dxs[pos] = osx[threadIdx.x]; dys[pos] = osy[threadIdx.x];
  }
  __syncthreads();
  return total;
}

// ---------------- per-wave conservative center prune ----------------
__device__ __forceinline__ int prune_centers(int n, const float* __restrict__ sxs,
    const float* __restrict__ sys, float minx, float maxx, float miny, float maxy,
    short* __restrict__ clist, int lane) {
  #pragma unroll
  for (int o = 32; o; o >>= 1) {
    minx = fminf(minx, __shfl_xor(minx, o));
    maxx = fmaxf(maxx, __shfl_xor(maxx, o));
    miny = fminf(miny, __shfl_xor(miny, o));
    maxy = fmaxf(maxy, __shfl_xor(maxy, o));
  }
  float cx0 = 0.5f * (minx + maxx), rx = 0.5f * (maxx - minx) + 0.5f;
  float cy0 = 0.5f * (miny + maxy), ry = 0.5f * (maxy - miny) + 0.5f;
  float lo[4];
  float ub = 3.4e38f;
  #pragma unroll
  for (int c = 0; c < 4; ++c) {
    int k = c * 64 + lane;
    float l = 3.4e38f;
    if (k < n) {
      float dx = fabsf(sxs[k] - cx0), dy = fabsf(sys[k] - cy0);
      float hx = dx + rx, hy = dy + ry;
      ub = fminf(ub, hx * hx + hy * hy);
      float lx = fmaxf(dx - rx, 0.f), ly = fmaxf(dy - ry, 0.f);
      l = lx * lx + ly * ly;
    }
    lo[c] = l;
  }
  #pragma unroll
  for (int o = 32; o; o >>= 1) ub = fminf(ub, __shfl_xor(ub, o));
  ub += 1.0f;
  int m = 0;
  unsigned long long lmlt = (1ull << lane) - 1ull;
  #pragma unroll
  for (int c = 0; c < 4; ++c) {                    // chunk-major => ascending k
    int k = c * 64 + lane;
    bool keep = (k < n) && (lo[c] <= ub);
    unsigned long long msk = __ballot(keep);
    if (keep) clist[m + (int)__popcll(msk & lmlt)] = (short)k;
    m += (int)__popcll(msk);
  }
  return m;
}

// exact argmin over pruned list (ascending original k, strict <), no-FMA math
__device__ __forceinline__ void assign4_exact(int m, const short* __restrict__ clist,
    const float* __restrict__ sxs, const float* __restrict__ sys,
    const float* ccx, const float* ccy, const unsigned char* cls, int* l) {
  float bd[4] = {3.4e38f, 3.4e38f, 3.4e38f, 3.4e38f};
  int bk[4] = {0, 0, 0, 0};
  for (int j = 0; j < m; ++j) {
    int k = (int)clist[j];
    float cxk = sxs[k], cyk = sys[k];
    #pragma unroll
    for (int q = 0; q < 4; ++q) {
      float dx = ccx[q] - cxk, dy = ccy[q] - cyk;
      float d = __fadd_rn(__fmul_rn(dx, dx), __fmul_rn(dy, dy));
      if (d < bd[q]) { bd[q] = d; bk[q] = k; }
    }
  }
  #pragma unroll
  for (int q = 0; q < 4; ++q) l[q] = (cls[q] >= 24) ? bk[q] + 1 : 0;
}

// shared assign body (w, h explicit; wave spans ONE row)
__device__ __forceinline__ void assign_body(int n, const float* sxs, const float* sys,
    short* clist_wv, int w, int h,
    const uchar4 sc4, const float4 r0, const float4 r1, int* l) {
  float ccx[4], ccy[4];
  #pragma unroll
  for (int q = 0; q < 4; ++q) {
    ccx[q] = (float)(w + q + 1) - ((const float*)&r0)[q];
    ccy[q] = (float)(h + 1) - ((const float*)&r1)[q];
  }
  float mnx = fminf(fminf(ccx[0], ccx[1]), fminf(ccx[2], ccx[3]));
  float mxx = fmaxf(fmaxf(ccx[0], ccx[1]), fmaxf(ccx[2], ccx[3]));
  float mny = fminf(fminf(ccy[0], ccy[1]), fminf(ccy[2], ccy[3]));
  float mxy = fmaxf(fmaxf(ccy[0], ccy[1]), fmaxf(ccy[2], ccy[3]));
  int lane = threadIdx.x & 63;
  int m = prune_centers(n, sxs, sys, mnx, mxx, mny, mxy, clist_wv, lane);
  unsigned char cls[4] = {sc4.x, sc4.y, sc4.z, sc4.w};
  assign4_exact(m, clist_wv, sxs, sys, ccx, ccy, cls, l);
}

// ---------------- K3: [topk] + assign0 + count/bbox (FOUR rows per block) ----------------
__global__ __launch_bounds__(ATH) void k_assign0(Prm p) {
  int b = blockIdx.y;
  int r = threadIdx.x >> 8;                        // 0..3: which row
  int h = (blockIdx.x << 2) | r;
  int w = (threadIdx.x & 255) * 4;
  __shared__ float sxs[TOPK], sys[TOPK];
  __shared__ short clists[ATH / 64][TOPK];
  __shared__ uint32_t sc[NSEG];
  __shared__ int sx0[NSEG], sx1[NSEG], sy0[NSEG], sy1[NSEG];
  __shared__ unsigned long long keysS[KSTG];
  for (int j = threadIdx.x; j < NSEG; j += ATH) {
    sc[j] = 0; sx0[j] = INTMAXC; sx1[j] = INTMINC; sy0[j] = INTMAXC; sy1[j] = INTMINC;
  }
  int n = block_topk(p, b, keysS, sxs, sys);       // full top-k list, label k+1
  size_t i = (size_t)b * NPIX + h * WW + w;
  const float* c0 = p.cr + (size_t)b * 2 * NPIX + h * WW + w;
  uchar4 sc4 = *reinterpret_cast<const uchar4*>(p.segc + i);
  float4 r0 = *reinterpret_cast<const float4*>(c0);
  float4 r1 = *reinterpret_cast<const float4*>(c0 + NPIX);
  int l[4];
  if (n == 0) { l[0] = l[1] = l[2] = l[3] = 0; }   // any_c false -> lab0 = 0
  else assign_body(n, sxs, sys, clists[threadIdx.x >> 6], w, h, sc4, r0, r1, l);
  *reinterpret_cast<int4*>(p.labA + i) = make_int4(l[0], l[1], l[2], l[3]);
  int cur = -1; uint32_t rc = 0; int rx0 = 0, rx1 = 0;
  #pragma unroll
  for (int q = 0; q < 4; ++q) {                    // run-merged LDS atomics (skip label 0)
    int lq = l[q], x = w + q;
    if (lq == cur) { rc++; rx1 = x; }
    else {
      if (cur > 0) { atomicAdd(&sc[cur], rc); atomicMin(&sx0[cur], rx0); atomicMax(&sx1[cur], rx1);
                     atomicMin(&sy0[cur], h); atomicMax(&sy1[cur], h); }
      cur = lq; rc = 1; rx0 = rx1 = x;
    }
  }
  if (cur > 0) { atomicAdd(&sc[cur], rc); atomicMin(&sx0[cur], rx0); atomicMax(&sx1[cur], rx1);
                 atomicMin(&sy0[cur], h); atomicMax(&sy1[cur], h); }
  __syncthreads();
  for (int j = threadIdx.x; j < NSEG; j += ATH) {
    if (sc[j]) {
      atomicAdd(&p.cnt0[b * NSEG + j], sc[j]);
      atomicMin(&p.ymin[b * NSEG + j], sy0[j]); atomicMax(&p.ymax[b * NSEG + j], sy1[j]);
      atomicMin(&p.xmin[b * NSEG + j], sx0[j]); atomicMax(&p.xmax[b * NSEG + j], sx1[j]);
    }
  }
}

// ---------------- K4: [topk + build1] + assign1 + count/cr-sums (4 rows) ----------------
__global__ __launch_bounds__(ATH) void k_assign1(Prm p) {
  int b = blockIdx.y;
  int r = threadIdx.x >> 8;
  int h = (blockIdx.x << 2) | r;
  int w = (threadIdx.x & 255) * 4;
  __shared__ float osx[TOPK], osy[TOPK];           // original slot coords
  __shared__ float sxs[TOPK], sys[TOPK];           // compacted good list
  __shared__ short clists[ATH / 64][TOPK];
  __shared__ uint32_t sc[NSEG];
  __shared__ unsigned long long ssx[NSEG], ssy[NSEG];
  __shared__ unsigned long long keysS[KSTG];
  __shared__ int wsumS[ATH / 64];
  for (int j = threadIdx.x; j < NSEG; j += ATH) { sc[j] = 0; ssx[j] = 0; ssy[j] = 0; }
  block_topk(p, b, keysS, osx, osy);
  int k = threadIdx.x;
  int good = 0;
  if (k < TOPK) {                                  // bbox-ratio pruning (exact ints)
    uint32_t c = p.cnt0[b * NSEG + k + 1];
    if (c > 0) {
      int j = b * NSEG + k + 1;
      float area = (float)((p.ymax[j] - p.ymin[j] + 1) * (p.xmax[j] - p.xmin[j] + 1));
      float ratio = (float)c / area;               // same IEEE div as reference
      good = (ratio > 0.3f) ? 1 : 0;
    }
  }
  int n = block_compact(good, osx, osy, sxs, sys, wsumS);
  size_t i = (size_t)b * NPIX + h * WW + w;
  const float* c0 = p.cr + (size_t)b * 2 * NPIX + h * WW + w;
  uchar4 sc4 = *reinterpret_cast<const uchar4*>(p.segc + i);
  float4 r0 = *reinterpret_cast<const float4*>(c0);
  float4 r1 = *reinterpret_cast<const float4*>(c0 + NPIX);
  int l[4];
  if (n == 0) { int4 f = *reinterpret_cast<const int4*>(p.labA + i); l[0]=f.x; l[1]=f.y; l[2]=f.z; l[3]=f.w; }
  else assign_body(n, sxs, sys, clists[threadIdx.x >> 6], w, h, sc4, r0, r1, l);
  *reinterpret_cast<int4*>(p.labB + i) = make_int4(l[0], l[1], l[2], l[3]);
  float crx[4] = {r0.x, r0.y, r0.z, r0.w};
  float cry[4] = {r1.x, r1.y, r1.z, r1.w};
  int cur = -1; uint32_t rc = 0; long long ax = 0, ay = 0;
  #pragma unroll
  for (int q = 0; q < 4; ++q) {
    int lq = l[q];
    long long qx = __double2ll_rn((double)crx[q] * 1048576.0);   // 2^20 fixed-point
    long long qy = __double2ll_rn((double)cry[q] * 1048576.0);
    if (lq == cur) { rc++; ax += qx; ay += qy; }
    else {
      if (cur > 0) { atomicAdd(&sc[cur], rc);
                     atomicAdd(&ssx[cur], (unsigned long long)ax);
                     atomicAdd(&ssy[cur], (unsigned long long)ay); }
      cur = lq; rc = 1; ax = qx; ay = qy;
    }
  }
  if (cur > 0) { atomicAdd(&sc[cur], rc);
                 atomicAdd(&ssx[cur], (unsigned long long)ax);
                 atomicAdd(&ssy[cur], (unsigned long long)ay); }
  __syncthreads();
  for (int j = threadIdx.x; j < NSEG; j += ATH) {
    if (sc[j]) {
      atomicAdd(&p.cnt2[b * NSEG + j], sc[j]);
      atomicAdd((unsigned long long*)&p.sxq[b * NSEG + j], ssx[j]);
      atomicAdd((unsigned long long*)&p.syq[b * NSEG + j], ssy[j]);
    }
  }
}

// ---------------- K5: [topk + build2] + assign2 + final + histogram (4 rows) ----------------
__global__ __launch_bounds__(ATH) void k_assign2(Prm p) {
  int b = blockIdx.y;
  int r = threadIdx.x >> 8;
  int h = (blockIdx.x << 2) | r;
  int w = (threadIdx.x & 255) * 4;
  __shared__ float osx[TOPK], osy[TOPK];
  __shared__ float sxs[TOPK], sys[TOPK];
  __shared__ short clists[ATH / 64][TOPK];
  __shared__ uint32_t sh[NSEG * NCC];
  __shared__ unsigned long long keysS[KSTG];
  __shared__ int wsumS[ATH / 64];
  for (int j = threadIdx.x; j < NSEG * NCC; j += ATH) sh[j] = 0;
  block_topk(p, b, keysS, osx, osy);
  int k = threadIdx.x;
  int good = 0;
  if (k < TOPK) {                                  // mean pruning (COMPACT-space stats)
    uint32_t c = p.cnt2[b * NSEG + k + 1];
    if (c > 0) {
      double inv = 1.0 / (double)c;
      double mx = ((double)p.sxq[b * NSEG + k + 1] * (1.0 / 1048576.0)) * inv;
      double my = ((double)p.syq[b * NSEG + k + 1] * (1.0 / 1048576.0)) * inv;
      good = (fabs(mx) < 10.0 && fabs(my) < 10.0) ? 1 : 0;
    }
  }
  int n = block_compact(good, osx, osy, sxs, sys, wsumS);  // ORIGINAL sorted coords
  size_t i = (size_t)b * NPIX + h * WW + w;
  const float* c0 = p.cr + (size_t)b * 2 * NPIX + h * WW + w;
  uchar4 sc4 = *reinterpret_cast<const uchar4*>(p.segc + i);
  float4 r0 = *reinterpret_cast<const float4*>(c0);
  float4 r1 = *reinterpret_cast<const float4*>(c0 + NPIX);
  int l[4];
  if (n == 0) { int4 f = *reinterpret_cast<const int4*>(p.labB + i); l[0]=f.x; l[1]=f.y; l[2]=f.z; l[3]=f.w; }
  else assign_body(n, sxs, sys, clists[threadIdx.x >> 6], w, h, sc4, r0, r1, l);
  *reinterpret_cast<int4*>(p.labA + i) = make_int4(l[0], l[1], l[2], l[3]);
  *reinterpret_cast<float4*>(p.out_final + i) =
      make_float4((float)l[0], (float)l[1], (float)l[2], (float)l[3]);
  unsigned char cls[4] = {sc4.x, sc4.y, sc4.z, sc4.w};
  int curk = -1; uint32_t rc = 0;
  #pragma unroll
  for (int q = 0; q < 4; ++q) {                    // run-merged hist atomics
    int key = l[q] * NCC + (int)cls[q];
    if (key == curk) { rc++; }
    else { if (curk >= 0) atomicAdd(&sh[curk], rc); curk = key; rc = 1; }
  }
  if (curk >= 0) atomicAdd(&sh[curk], rc);
  __syncthreads();
  for (int j = threadIdx.x; j < NSEG * NCC; j += ATH)
    if (sh[j]) atomicAdd(&p.hist[(size_t)b * NSEG * NCC + j], sh[j]);
}

// ---------------- K6: [mode] + prob-sum per label ----------------
__global__ __launch_bounds__(256) void k_sg(Prm p) {
  int b = blockIdx.y;
  __shared__ unsigned long long ss[NSEG];
  __shared__ int icS[NSEG];
  for (int j = threadIdx.x; j < NSEG; j += 256) {
    const uint32_t* hr = p.hist + ((size_t)b * NSEG + j) * NCC;
    uint32_t bv = hr[0], ssum = hr[0]; int bc = 0;
    #pragma unroll
    for (int c = 1; c < NCC; ++c) {
      uint32_t v = hr[c]; ssum += v;
      if (v > bv) { bv = v; bc = c; }              // first-max tie-break
    }
    icS[j] = bc;
    ss[j] = 0;
    if (blockIdx.x == 0) {                         // single writer per batch
      p.out_instc[b * NSEG + j] = (float)bc;
      p.out_cntf[b * NSEG + j] = (float)ssum;
    }
  }
  __syncthreads();
  int pp = (blockIdx.x * 256 + threadIdx.x) * 4;
  size_t i = (size_t)b * NPIX + pp;
  int4 l4 = *reinterpret_cast<const int4*>(p.labA + i);
  float4 iv = *reinterpret_cast<const float4*>(p.pinv + i);
  const float* sb = p.seg + (size_t)b * NCC * NPIX + pp;
  int lA[4] = {l4.x, l4.y, l4.z, l4.w};
  float ivA[4] = {iv.x, iv.y, iv.z, iv.w};
  int cur = -1; long long acc = 0;                 // label 0 IS included here
  #pragma unroll
  for (int q = 0; q < 4; ++q) {
    int lq = lA[q];
    int c = icS[lq];
    float x = sb[(size_t)c * NPIX + q];
    float pr = __expf(x) * ivA[q];                 // == exp(x - m)/sum(exp(x - m))
    long long qv = __double2ll_rn((double)pr * 4294967296.0);   // 2^32 fixed-point
    if (lq == cur) acc += qv;
    else { if (cur >= 0) atomicAdd(&ss[cur], (unsigned long long)acc); cur = lq; acc = qv; }
  }
  if (cur >= 0) atomicAdd(&ss[cur], (unsigned long long)acc);
  __syncthreads();
  for (int j = threadIdx.x; j < NSEG; j += 256)
    if (ss[j]) atomicAdd((unsigned long long*)&p.Ssel[b * NSEG + j], ss[j]);
}

// ---------------- K7: seg_prob = Ssel / max(cntf,1) ----------------
__global__ void k_prob(Prm p) {
  int i = blockIdx.x * blockDim.x + threadIdx.x;
  if (i >= BB * NSEG) return;
  double s = (double)p.Ssel[i] * (1.0 / 4294967296.0);
  float c = p.out_cntf[i];
  p.out_prob[i] = (float)(s / (double)fmaxf(c, 1.0f));
}

extern "C" void kernel_launch(void* const* d_in, const int* in_sizes, int n_in,
                              void* d_out, int out_size, void* d_ws, size_t ws_size,
                              hipStream_t stream) {
  float* out = (float*)d_out;
  Prm p;
  p.seg = (const float*)d_in[0];
  p.cr  = (const float*)d_in[2];
  p.out_final  = out;
  p.out_segmap = out + (size_t)BB * NPIX;
  p.out_instc  = out + (size_t)2 * BB * NPIX;
  p.out_prob   = p.out_instc + BB * NSEG;
  p.out_cntf   = p.out_prob + BB * NSEG;

  char* ws = (char*)d_ws;
  size_t off = 0;
  auto take = [&](size_t n) { size_t o = off; off += (n + 255) & ~(size_t)255; return o; };

  p.labA = (int32_t*)(ws + take((size_t)BB * NPIX * 4));  // votes -> lab0 -> final
  p.labB = (int32_t*)(ws + take((size_t)BB * NPIX * 4));  // lab1
  p.pinv = (float*)(ws + take((size_t)BB * NPIX * 4));
  p.segc = (uint8_t*)(ws + take((size_t)BB * NPIX));
  p.ymin = (int*)(ws + take(BB * NSEG * 4));               // INTMAX/MIN init (outside zero span)
  p.ymax = (int*)(ws + take(BB * NSEG * 4));
  p.xmin = (int*)(ws + take(BB * NSEG * 4));
  p.xmax = (int*)(ws + take(BB * NSEG * 4));

  size_t zero_begin = off;
  p.cand_cnt = (uint32_t*)(ws + take(BB * 4));
  p.cand_val = (uint32_t*)(ws + take((size_t)BB * CAP * 4));
  p.cand_idx = (uint32_t*)(ws + take((size_t)BB * CAP * 4));
  p.cnt0 = (uint32_t*)(ws + take(BB * NSEG * 4));
  p.cnt2 = (uint32_t*)(ws + take(BB * NSEG * 4));
  p.sxq = (long long*)(ws + take(BB * NSEG * 8));
  p.syq = (long long*)(ws + take(BB * NSEG * 8));
  p.hist = (uint32_t*)(ws + take((size_t)BB * NSEG * NCC * 4));
  p.Ssel = (long long*)(ws + take(BB * NSEG * 8));
  size_t zero_end = off;

  if (ws_size < off) return;  // workspace too small -> fail visibly

  p.zero4 = (uint4*)(ws + zero_begin);
  p.nzero4 = (int)((zero_end - zero_begin) / 16);  // 256-aligned span

  k_clear<<<BB * NPIX / 4 / 256, 256, 0, stream>>>(p);
  k_pixel<<<BB * NPIX / 4 / 256, 256, 0, stream>>>(p);
  k_nms<<<BB * NPIX / 4 / 256, 256, 0, stream>>>(p);
  dim3 agrid(HH / 4, BB);                          // 4 rows per block, 1024 threads
  k_assign0<<<agrid, ATH, 0, stream>>>(p);                 // + topk prologue
  k_assign1<<<agrid, ATH, 0, stream>>>(p);                 // + topk/build1 prologue
  k_assign2<<<agrid, ATH, 0, stream>>>(p);                 // + topk/build2 prologue
  k_sg<<<dim3(NPIX / 1024, BB), 256, 0, stream>>>(p);      // + mode prologue
  k_prob<<<(BB * NSEG + 255) / 256, 256, 0, stream>>>(p);
}